// Round 4
// baseline (706.231 us; speedup 1.0000x reference)
//
#include <hip/hip_runtime.h>

#define CC 128

typedef __attribute__((ext_vector_type(8))) short bf16x8;
typedef __attribute__((ext_vector_type(4))) float f32x4;

static __device__ __forceinline__ float lrelu(float v){ return v > 0.f ? v : 0.2f*v; }
static __device__ __forceinline__ unsigned short f2bf(float f){
  unsigned u = __float_as_uint(f);
  unsigned r = (u + 0x7fffu + ((u >> 16) & 1u)) >> 16;
  return (unsigned short)r;
}
static __device__ __forceinline__ float bf2f(unsigned short s){
  return __uint_as_float(((unsigned)s) << 16);
}

// ---------------- GEMM: out[N,128] = (RELU?relu(in):in)[N,128] @ W[128,128]
template<bool RELU, bool OBF16>
__global__ __launch_bounds__(256) void gemm128(const float* __restrict__ in,
                                               const float* __restrict__ W,
                                               void* __restrict__ outv){
  __shared__ float4 xs4[32*33];
  const int tid = threadIdx.x;
  const long row0 = (long)blockIdx.x * 32;
  const float4* in4 = (const float4*)(in + row0*CC);
  #pragma unroll
  for (int i=0;i<4;i++){
    int f = tid + i*256;
    float4 v = in4[f];
    if (RELU){ v.x=fmaxf(v.x,0.f); v.y=fmaxf(v.y,0.f); v.z=fmaxf(v.z,0.f); v.w=fmaxf(v.w,0.f); }
    xs4[(f>>5)*33 + (f&31)] = v;
  }
  __syncthreads();
  const int tc = tid & 31;
  const int tr = tid >> 5;
  const float4* W4 = (const float4*)W;
  float acc[4][4] = {};
  #pragma unroll 2
  for (int kq=0; kq<32; kq++){
    float4 w0 = W4[(kq*4+0)*32 + tc];
    float4 w1 = W4[(kq*4+1)*32 + tc];
    float4 w2 = W4[(kq*4+2)*32 + tc];
    float4 w3 = W4[(kq*4+3)*32 + tc];
    #pragma unroll
    for (int i=0;i<4;i++){
      float4 xv = xs4[(tr*4+i)*33 + kq];
      acc[i][0] += xv.x*w0.x + xv.y*w1.x + xv.z*w2.x + xv.w*w3.x;
      acc[i][1] += xv.x*w0.y + xv.y*w1.y + xv.z*w2.y + xv.w*w3.y;
      acc[i][2] += xv.x*w0.z + xv.y*w1.z + xv.z*w2.z + xv.w*w3.z;
      acc[i][3] += xv.x*w0.w + xv.y*w1.w + xv.z*w2.w + xv.w*w3.w;
    }
  }
  if (OBF16){
    unsigned short* out = (unsigned short*)outv;
    #pragma unroll
    for (int i=0;i<4;i++){
      ushort4 o; o.x=f2bf(acc[i][0]); o.y=f2bf(acc[i][1]); o.z=f2bf(acc[i][2]); o.w=f2bf(acc[i][3]);
      *(ushort4*)&out[(row0 + tr*4 + i)*CC + tc*4] = o;
    }
  } else {
    float4* out4 = (float4*)((float*)outv + row0*CC);
    #pragma unroll
    for (int i=0;i<4;i++)
      out4[(tr*4+i)*32 + tc] = make_float4(acc[i][0],acc[i][1],acc[i][2],acc[i][3]);
  }
}

// ---------------- per-row dot with two vectors
__global__ __launch_bounds__(256) void rowdot2(const float* __restrict__ xw,
                                               const float* __restrict__ a1,
                                               const float* __restrict__ a2,
                                               float* __restrict__ as_, float* __restrict__ ad_){
  const int lane = threadIdx.x & 63;
  const long row = (long)blockIdx.x*4 + (threadIdx.x >> 6);
  float2 v  = ((const float2*)(xw + row*CC))[lane];
  float2 w1 = ((const float2*)a1)[lane];
  float2 w2 = ((const float2*)a2)[lane];
  float s1 = v.x*w1.x + v.y*w1.y;
  float s2 = v.x*w2.x + v.y*w2.y;
  #pragma unroll
  for (int off=32; off; off>>=1){
    s1 += __shfl_xor(s1, off);
    s2 += __shfl_xor(s2, off);
  }
  if (lane==0){ as_[row]=s1; ad_[row]=s2; }
}

// ---------------- CSR build (edge_index identical for both layers)
__global__ void zero_int(int* __restrict__ p, int n){
  int i = blockIdx.x*256 + threadIdx.x;
  if (i < n) p[i] = 0;
}
__global__ void csr_hist(const int* __restrict__ ei, int* __restrict__ deg, int E){
  int e = blockIdx.x*256 + threadIdx.x;
  if (e < E) atomicAdd(&deg[ei[E + e]], 1);
}
__global__ __launch_bounds__(256) void csr_scan(const int* __restrict__ deg,
                                                int* __restrict__ rowptr,
                                                int* __restrict__ cursor, int N){
  __shared__ int part[257];
  const int t = threadIdx.x;
  const int per = N / 256;
  const int base = t*per;
  int s = 0;
  for (int j=0;j<per;j++) s += deg[base+j];
  part[t+1] = s;
  if (t==0) part[0] = 0;
  __syncthreads();
  if (t==0){
    for (int i=1;i<=256;i++) part[i] += part[i-1];
  }
  __syncthreads();
  int run = part[t];
  for (int j=0;j<per;j++){
    rowptr[base+j] = run;
    cursor[base+j] = run;
    run += deg[base+j];
  }
  if (t==255) rowptr[N] = run;
}
__global__ void csr_fill(const int* __restrict__ ei, int* __restrict__ cursor,
                         int* __restrict__ csrc, int E){
  int e = blockIdx.x*256 + threadIdx.x;
  if (e < E){
    int d = ei[E + e];
    int slot = atomicAdd(&cursor[d], 1);
    csrc[slot] = ei[e];
  }
}

// ---------------- fused GAT: online segment-softmax + aggregate (no atomics)
__global__ __launch_bounds__(256) void gat_gather(
    const int* __restrict__ rowptr, const int* __restrict__ csrc,
    const float* __restrict__ as_, const float* __restrict__ ad_,
    const float* __restrict__ xw, const float* __restrict__ b,
    float* __restrict__ out, int N){
  const int lane = threadIdx.x & 63;
  const int dst = blockIdx.x*4 + (threadIdx.x >> 6);
  const float adv = ad_[dst];
  float m = lrelu(as_[dst] + adv);
  float l = 1.f;
  float2 acc = ((const float2*)(xw + (size_t)dst*CC))[lane];
  const int kb = rowptr[dst], ke = rowptr[dst+1];
  int k = kb;
  int s_cur = 0; float a_cur = 0.f;
  if (k < ke){ s_cur = csrc[k]; a_cur = as_[s_cur]; }
  while (k < ke){
    int k1 = k + 1;
    int s_nxt = 0; float a_nxt = 0.f;
    if (k1 < ke){ s_nxt = csrc[k1]; a_nxt = as_[s_nxt]; }
    float2 v = ((const float2*)(xw + (size_t)s_cur*CC))[lane];
    float e = lrelu(a_cur + adv);
    float mn = fmaxf(m, e);
    float fr = __expf(m - mn);
    float p  = __expf(e - mn);
    acc.x = acc.x*fr + p*v.x;
    acc.y = acc.y*fr + p*v.y;
    l = l*fr + p;
    m = mn;
    s_cur = s_nxt; a_cur = a_nxt; k = k1;
  }
  float inv = 1.f / l;
  float2 bb = ((const float2*)b)[lane];
  float2 r; r.x = acc.x*inv + bb.x; r.y = acc.y*inv + bb.y;
  ((float2*)(out + (size_t)dst*CC))[lane] = r;
}

// ---------------- h (f32) -> HbT (tiled H-fragment image) + HTb (bf16 [C][N])
// HbT per 64-key tile: 1024 uint4, unit u=((key>>4)*4+(c8>>2))*64+(c8&3)*16+(key&15)
// holds Hb[key][c8*8..+7]. HTb row-major transposed.
__global__ __launch_bounds__(256) void convert_pack(const float* __restrict__ h,
                                                    unsigned short* __restrict__ HbT,
                                                    unsigned short* __restrict__ HTb, int N){
  int idx = blockIdx.x*256 + threadIdx.x;
  const int nH = N*16;            // uint4 count of H image
  if (idx < nH){
    int tile = idx >> 10, u = idx & 1023;
    int a = u>>6, bb = (u>>4)&3, c = u&15;
    int key = tile*64 + (a>>2)*16 + c;
    int c8 = (a&3)*4 + bb;
    const float* src = h + (size_t)key*CC + c8*8;
    float4 v0 = *(const float4*)src;
    float4 v1 = *(const float4*)(src+4);
    ushort4 o0, o1;
    o0.x=f2bf(v0.x); o0.y=f2bf(v0.y); o0.z=f2bf(v0.z); o0.w=f2bf(v0.w);
    o1.x=f2bf(v1.x); o1.y=f2bf(v1.y); o1.z=f2bf(v1.z); o1.w=f2bf(v1.w);
    *(ushort4*)&HbT[(size_t)idx*8]     = o0;
    *(ushort4*)&HbT[(size_t)idx*8 + 4] = o1;
  } else {
    int j = idx - nH;
    int nk = N >> 3;
    int c = j / nk;
    int kb = j - c*nk;
    int key = kb*8;
    float f[8];
    #pragma unroll
    for (int r=0;r<8;r++) f[r] = h[(size_t)(key+r)*CC + c];
    ushort4 o0, o1;
    o0.x=f2bf(f[0]); o0.y=f2bf(f[1]); o0.z=f2bf(f[2]); o0.w=f2bf(f[3]);
    o1.x=f2bf(f[4]); o1.y=f2bf(f[5]); o1.z=f2bf(f[6]); o1.w=f2bf(f[7]);
    *(ushort4*)&HTb[(size_t)c*N + key]     = o0;
    *(ushort4*)&HTb[(size_t)c*N + key + 4] = o1;
  }
}

// ---------------- MFMA flash attention (bf16), KV-split, defer-max, setprio
__global__ __launch_bounds__(256,3) void attn_mfma(
    const unsigned short* __restrict__ Qb, const uint4* __restrict__ HbTile,
    const unsigned short* __restrict__ HTb,
    unsigned short* __restrict__ opW, float* __restrict__ ml, int N, int nsplit){
  __shared__ uint4 SH[2048];   // [0,1024) H frags, [1024,2048) HT frags
  __shared__ uint4 PT[1024];   // per-wave 256 uint4

  const int tid = threadIdx.x;
  const int lane = tid & 63, w = tid >> 6;
  const int g = lane >> 4, c15 = lane & 15;

  // XCD-aware bijective swizzle (nwg % 8 == 0 by construction)
  const int nwg = gridDim.x * gridDim.y;
  const int flat = blockIdx.y * gridDim.x + blockIdx.x;
  const int swz = (flat & 7) * (nwg >> 3) + (flat >> 3);
  const int qb0 = (swz & 127) * 128;
  const int split = swz >> 7;

  const int ntt = N >> 6;
  const int tb = (ntt * split) / nsplit;
  const int te = (ntt * (split + 1)) / nsplit;
  const float RS = 0.088388347648318447f;   // 1/sqrt(128)

  bf16x8 qf[2][4];
  const int qrow_base = qb0 + w*32;
  #pragma unroll
  for (int qt=0; qt<2; qt++)
    #pragma unroll
    for (int ks=0; ks<4; ks++)
      qf[qt][ks] = *(const bf16x8*)&Qb[(size_t)(qrow_base + qt*16 + c15)*CC + ks*32 + g*8];

  f32x4 zero4 = {0.f,0.f,0.f,0.f};
  f32x4 acc_o[8][2];
  #pragma unroll
  for (int a=0;a<8;a++){ acc_o[a][0]=zero4; acc_o[a][1]=zero4; }
  float m_[2] = {-3.0e38f, -3.0e38f};
  float l_[2] = {0.f, 0.f};

  int stU[4];
  #pragma unroll
  for (int i=0;i<4;i++){
    int f = tid + i*256;
    int c = f>>3, k8 = f&7;
    stU[i] = ((c>>4)*2 + (k8>>2))*64 + (k8&3)*16 + (c&15);
  }

  const int nk8 = N >> 3;
  const uint4* HT4base = (const uint4*)HTb;   // view: row c has nk8 uint4
  uint4 G[8];
  {
    const uint4* hb = HbTile + (size_t)tb*1024;
    const int kofs = (tb*64) >> 3;
    #pragma unroll
    for (int i=0;i<4;i++){
      int f = tid + i*256;
      G[i]   = hb[f];
      G[4+i] = HT4base[(size_t)(f>>3)*nk8 + kofs + (f&7)];
    }
  }

  for (int t=tb; t<te; t++){
    __syncthreads();                    // all waves done reading SH
    #pragma unroll
    for (int i=0;i<4;i++) SH[tid + i*256] = G[i];          // linear: conflict-free
    #pragma unroll
    for (int i=0;i<4;i++) SH[1024 + stU[i]] = G[4+i];
    if (t+1 < te){
      const uint4* hb = HbTile + (size_t)(t+1)*1024;
      const int kofs = ((t+1)*64) >> 3;
      #pragma unroll
      for (int i=0;i<4;i++){
        int f = tid + i*256;
        G[i]   = hb[f];
        G[4+i] = HT4base[(size_t)(f>>3)*nk8 + kofs + (f&7)];
      }
    }
    __syncthreads();                    // staged tile visible

    // ---- S phase
    f32x4 accs[4][2];
    #pragma unroll
    for (int kt=0; kt<4; kt++){ accs[kt][0]=zero4; accs[kt][1]=zero4; }
    __builtin_amdgcn_s_setprio(1);
    #pragma unroll
    for (int kt=0; kt<4; kt++)
      #pragma unroll
      for (int ks=0; ks<4; ks++){
        bf16x8 hf = *(const bf16x8*)&SH[(kt*4+ks)*64 + lane];
        accs[kt][0] = __builtin_amdgcn_mfma_f32_16x16x32_bf16(hf, qf[0][ks], accs[kt][0], 0,0,0);
        accs[kt][1] = __builtin_amdgcn_mfma_f32_16x16x32_bf16(hf, qf[1][ks], accs[kt][1], 0,0,0);
      }
    __builtin_amdgcn_s_setprio(0);

    // ---- online softmax with defer-max (skip rescale when max growth <= 8)
    float tm[2];
    #pragma unroll
    for (int qt=0; qt<2; qt++){
      float v = accs[0][qt][0];
      #pragma unroll
      for (int kt=0; kt<4; kt++)
        #pragma unroll
        for (int r=0; r<4; r++) v = fmaxf(v, accs[kt][qt][r]);
      v *= RS;
      v = fmaxf(v, __shfl_xor(v, 16));
      v = fmaxf(v, __shfl_xor(v, 32));
      tm[qt] = v;
    }
    if (!__all((tm[0] <= m_[0] + 8.f) & (tm[1] <= m_[1] + 8.f))){
      #pragma unroll
      for (int qt=0; qt<2; qt++){
        float mn = fmaxf(m_[qt], tm[qt]);
        float fr = __expf(m_[qt] - mn);
        m_[qt] = mn;
        l_[qt] *= fr;
        #pragma unroll
        for (int a=0;a<8;a++){
          acc_o[a][qt][0]*=fr; acc_o[a][qt][1]*=fr;
          acc_o[a][qt][2]*=fr; acc_o[a][qt][3]*=fr;
        }
      }
    }
    #pragma unroll
    for (int qt=0; qt<2; qt++){
      float ps = 0.f;
      #pragma unroll
      for (int kt=0; kt<4; kt++)
        #pragma unroll
        for (int r=0; r<4; r++){
          float p = __expf(accs[kt][qt][r]*RS - m_[qt]);
          accs[kt][qt][r] = p;
          ps += p;
        }
      ps += __shfl_xor(ps, 16);
      ps += __shfl_xor(ps, 32);
      l_[qt] += ps;
    }

    // ---- P^T -> per-wave LDS fragment image, read back as B-frags
    unsigned short* pt16 = (unsigned short*)&PT[w*256];
    #pragma unroll
    for (int kt=0; kt<4; kt++)
      #pragma unroll
      for (int qt=0; qt<2; qt++){
        ushort4 pk;
        pk.x = f2bf(accs[kt][qt][0]); pk.y = f2bf(accs[kt][qt][1]);
        pk.z = f2bf(accs[kt][qt][2]); pk.w = f2bf(accs[kt][qt][3]);
        int addr = ((kt>>1)*2 + qt)*512 + (((kt&1)*2 + (g>>1))*16 + c15)*8 + (g&1)*4;
        *(ushort4*)&pt16[addr] = pk;
      }
    bf16x8 ptf[2][2];
    const uint4* ptv = &PT[w*256];
    #pragma unroll
    for (int ks2=0; ks2<2; ks2++)
      #pragma unroll
      for (int qt=0; qt<2; qt++)
        ptf[ks2][qt] = *(const bf16x8*)&ptv[(ks2*2+qt)*64 + lane];

    // ---- PV
    __builtin_amdgcn_s_setprio(1);
    #pragma unroll
    for (int ct2=0; ct2<8; ct2++)
      #pragma unroll
      for (int ks2=0; ks2<2; ks2++){
        bf16x8 hf = *(const bf16x8*)&SH[1024 + (ct2*2+ks2)*64 + lane];
        acc_o[ct2][0] = __builtin_amdgcn_mfma_f32_16x16x32_bf16(hf, ptf[ks2][0], acc_o[ct2][0], 0,0,0);
        acc_o[ct2][1] = __builtin_amdgcn_mfma_f32_16x16x32_bf16(hf, ptf[ks2][1], acc_o[ct2][1], 0,0,0);
      }
    __builtin_amdgcn_s_setprio(0);
  }

  // ---- epilogue: normalized bf16 partials + (m,l)
  unsigned short* opBase = opW + (size_t)split*N*CC;
  #pragma unroll
  for (int qt=0; qt<2; qt++){
    float inv = 1.f / l_[qt];
    int qrow = qrow_base + qt*16 + c15;
    #pragma unroll
    for (int ct2=0; ct2<8; ct2++){
      ushort4 o;
      o.x = f2bf(acc_o[ct2][qt][0]*inv); o.y = f2bf(acc_o[ct2][qt][1]*inv);
      o.z = f2bf(acc_o[ct2][qt][2]*inv); o.w = f2bf(acc_o[ct2][qt][3]*inv);
      *(ushort4*)&opBase[(size_t)qrow*CC + ct2*16 + g*4] = o;
    }
    if (g == 0)
      ((float2*)ml)[(size_t)split*N + qrow] = make_float2(m_[qt], l_[qt]);
  }
}

// ---------------- merge partials + att_bias + residual + LayerNorm
template<int NS>
__global__ __launch_bounds__(256) void merge_ln(
    const unsigned short* __restrict__ opW, const float* __restrict__ ml,
    const float* __restrict__ x, const float* __restrict__ ab,
    const float* __restrict__ gam, const float* __restrict__ bet,
    float* __restrict__ out, int N){
  const int lane = threadIdx.x & 63;
  const long row = (long)blockIdx.x*4 + (threadIdx.x >> 6);
  float mm[NS], ll[NS];
  float M = -3.0e38f;
  #pragma unroll
  for (int i=0;i<NS;i++){
    float2 v = ((const float2*)ml)[(size_t)i*N + row];
    mm[i]=v.x; ll[i]=v.y;
    M = fmaxf(M, v.x);
  }
  float den = 0.f;
  float wgt[NS];
  #pragma unroll
  for (int i=0;i<NS;i++){ wgt[i] = __expf(mm[i]-M)*ll[i]; den += wgt[i]; }
  float invd = 1.f/den;
  float o0 = 0.f, o1 = 0.f;
  #pragma unroll
  for (int i=0;i<NS;i++){
    unsigned u = *(const unsigned*)&opW[((size_t)i*N + row)*CC + lane*2];
    float c = wgt[i]*invd;
    o0 += c * bf2f((unsigned short)(u & 0xffffu));
    o1 += c * bf2f((unsigned short)(u >> 16));
  }
  float2 xb = ((const float2*)(x + row*CC))[lane];
  float2 bb = ((const float2*)ab)[lane];
  float a0 = o0 + bb.x + xb.x;
  float a1 = o1 + bb.y + xb.y;
  float s = a0 + a1, ss = a0*a0 + a1*a1;
  #pragma unroll
  for (int off=32; off; off>>=1){ s += __shfl_xor(s,off); ss += __shfl_xor(ss,off); }
  float mu  = s * (1.f/128.f);
  float var = ss * (1.f/128.f) - mu*mu;
  float rstd = rsqrtf(var + 1e-5f);
  float2 gg = ((const float2*)gam)[lane];
  float2 b2 = ((const float2*)bet)[lane];
  float2 r;
  r.x = (a0 - mu)*rstd*gg.x + b2.x;
  r.y = (a1 - mu)*rstd*gg.y + b2.y;
  ((float2*)(out + row*CC))[lane] = r;
}

extern "C" void kernel_launch(void* const* d_in, const int* in_sizes, int n_in,
                              void* d_out, int out_size, void* d_ws, size_t ws_size,
                              hipStream_t stream) {
  const float* x   = (const float*)d_in[0];
  const int*   ei  = (const int*)d_in[1];
  const float* W1  = (const float*)d_in[3];
  const float* a_s1= (const float*)d_in[4];
  const float* a_d1= (const float*)d_in[5];
  const float* b1  = (const float*)d_in[6];
  const float* W2  = (const float*)d_in[7];
  const float* a_s2= (const float*)d_in[8];
  const float* a_d2= (const float*)d_in[9];
  const float* b2  = (const float*)d_in[10];
  const float* Wa  = (const float*)d_in[11];
  const float* ab  = (const float*)d_in[12];
  const float* g   = (const float*)d_in[13];
  const float* be  = (const float*)d_in[14];
  float* out = (float*)d_out;

  const int N = in_sizes[0] / CC;
  const int E = in_sizes[1] / 2;
  const size_t MB = 1024*1024;
  const size_t KB = 1024;

  char* base = (char*)d_ws;
  // GAT phase:  [0,8M) xw f32 | [8,16M) h f32 | [16,18M) csrc | [18M..) csr meta + as/ad
  // attn phase: [0,4M) HbT tiled | [4,8M) HTb | [8, 8+4ns M) op partials | then ml
  //             Qb (bf16) lives in d_out (dead before merge_ln writes out)
  float* xw   = (float*)(base + 0);
  float* h    = (float*)(base + 8*MB);
  int* csrc   = (int*)(base + 16*MB);
  int* rowptr = (int*)(base + 18*MB);
  int* cursor = (int*)(base + 18*MB + 128*KB);
  int* deg    = (int*)(base + 18*MB + 256*KB);
  float* as_  = (float*)(base + 18*MB + 384*KB);
  float* ad_  = (float*)(base + 18*MB + 512*KB);
  unsigned short* HbT = (unsigned short*)(base + 0);
  unsigned short* HTb = (unsigned short*)(base + 4*MB);
  unsigned short* opW = (unsigned short*)(base + 8*MB);
  unsigned short* QbD = (unsigned short*)d_out;

  const size_t need6 = (8 + 24)*MB + (size_t)6*N*2*sizeof(float);
  const int ns = (ws_size >= need6) ? 6 : 4;
  float* ml = (float*)(base + 8*MB + (size_t)ns*4*MB);

  dim3 B(256);

  // ---- CSR build (shared by both GAT layers)
  zero_int<<<(N+255)/256, B, 0, stream>>>(deg, N);
  csr_hist<<<(E+255)/256, B, 0, stream>>>(ei, deg, E);
  csr_scan<<<1, B, 0, stream>>>(deg, rowptr, cursor, N);
  csr_fill<<<(E+255)/256, B, 0, stream>>>(ei, cursor, csrc, E);

  // ---- GAT layer 1
  gemm128<false,false><<<N/32, B, 0, stream>>>(x, W1, xw);
  rowdot2<<<N/4, B, 0, stream>>>(xw, a_s1, a_d1, as_, ad_);
  gat_gather<<<N/4, B, 0, stream>>>(rowptr, csrc, as_, ad_, xw, b1, h, N);

  // ---- GAT layer 2 (relu fused into gemm)
  gemm128<true,false><<<N/32, B, 0, stream>>>(h, W2, xw);
  rowdot2<<<N/4, B, 0, stream>>>(xw, a_s2, a_d2, as_, ad_);
  gat_gather<<<N/4, B, 0, stream>>>(rowptr, csrc, as_, ad_, xw, b2, h, N);

  // ---- temporal attention (bf16 MFMA flash)
  gemm128<false,true><<<N/32, B, 0, stream>>>(h, Wa, QbD);        // q bf16 -> d_out scratch
  convert_pack<<<(N*32)/256, B, 0, stream>>>(h, HbT, HTb, N);     // h -> tiled H image + HT
  attn_mfma<<<dim3(N/128, ns), B, 0, stream>>>(QbD, (const uint4*)HbT, HTb, opW, ml, N, ns);

  // ---- merge + att_bias + residual + LayerNorm
  if (ns == 6)
    merge_ln<6><<<N/4, B, 0, stream>>>(opW, ml, x, ab, g, be, out, N);
  else
    merge_ln<4><<<N/4, B, 0, stream>>>(opW, ml, x, ab, g, be, out, N);
}

// Round 5
// 459.231 us; speedup vs baseline: 1.5379x; 1.5379x over previous
//
#include <hip/hip_runtime.h>

#define CC 128

typedef __attribute__((ext_vector_type(8))) short bf16x8;
typedef __attribute__((ext_vector_type(4))) float f32x4;
typedef __attribute__((ext_vector_type(16))) float f32x16;

static __device__ __forceinline__ float lrelu(float v){ return v > 0.f ? v : 0.2f*v; }
static __device__ __forceinline__ unsigned short f2bf(float f){
  unsigned u = __float_as_uint(f);
  unsigned r = (u + 0x7fffu + ((u >> 16) & 1u)) >> 16;
  return (unsigned short)r;
}
static __device__ __forceinline__ float bf2f(unsigned short s){
  return __uint_as_float(((unsigned)s) << 16);
}
static __device__ __forceinline__ unsigned packbf(float lo, float hi){
  return (unsigned)f2bf(lo) | ((unsigned)f2bf(hi) << 16);
}

// Q pre-scale: 1/sqrt(128) * log2(e)  (softmax runs in exp2 domain)
#define QSCALE (0.08838834764831845f * 1.4426950408889634f)

// ---------------- GEMM: out[N,128] = (RELU?relu(in):in)[N,128] @ W[128,128]
template<bool RELU, bool OBF16>
__global__ __launch_bounds__(256) void gemm128(const float* __restrict__ in,
                                               const float* __restrict__ W,
                                               void* __restrict__ outv){
  __shared__ float4 xs4[32*33];
  const int tid = threadIdx.x;
  const long row0 = (long)blockIdx.x * 32;
  const float4* in4 = (const float4*)(in + row0*CC);
  #pragma unroll
  for (int i=0;i<4;i++){
    int f = tid + i*256;
    float4 v = in4[f];
    if (RELU){ v.x=fmaxf(v.x,0.f); v.y=fmaxf(v.y,0.f); v.z=fmaxf(v.z,0.f); v.w=fmaxf(v.w,0.f); }
    xs4[(f>>5)*33 + (f&31)] = v;
  }
  __syncthreads();
  const int tc = tid & 31;
  const int tr = tid >> 5;
  const float4* W4 = (const float4*)W;
  float acc[4][4] = {};
  #pragma unroll 2
  for (int kq=0; kq<32; kq++){
    float4 w0 = W4[(kq*4+0)*32 + tc];
    float4 w1 = W4[(kq*4+1)*32 + tc];
    float4 w2 = W4[(kq*4+2)*32 + tc];
    float4 w3 = W4[(kq*4+3)*32 + tc];
    #pragma unroll
    for (int i=0;i<4;i++){
      float4 xv = xs4[(tr*4+i)*33 + kq];
      acc[i][0] += xv.x*w0.x + xv.y*w1.x + xv.z*w2.x + xv.w*w3.x;
      acc[i][1] += xv.x*w0.y + xv.y*w1.y + xv.z*w2.y + xv.w*w3.y;
      acc[i][2] += xv.x*w0.z + xv.y*w1.z + xv.z*w2.z + xv.w*w3.z;
      acc[i][3] += xv.x*w0.w + xv.y*w1.w + xv.z*w2.w + xv.w*w3.w;
    }
  }
  if (OBF16){
    unsigned short* out = (unsigned short*)outv;
    #pragma unroll
    for (int i=0;i<4;i++){
      ushort4 o;
      o.x=f2bf(acc[i][0]*QSCALE); o.y=f2bf(acc[i][1]*QSCALE);
      o.z=f2bf(acc[i][2]*QSCALE); o.w=f2bf(acc[i][3]*QSCALE);
      *(ushort4*)&out[(row0 + tr*4 + i)*CC + tc*4] = o;
    }
  } else {
    float4* out4 = (float4*)((float*)outv + row0*CC);
    #pragma unroll
    for (int i=0;i<4;i++)
      out4[(tr*4+i)*32 + tc] = make_float4(acc[i][0],acc[i][1],acc[i][2],acc[i][3]);
  }
}

// ---------------- per-row dot with two vectors
__global__ __launch_bounds__(256) void rowdot2(const float* __restrict__ xw,
                                               const float* __restrict__ a1,
                                               const float* __restrict__ a2,
                                               float* __restrict__ as_, float* __restrict__ ad_){
  const int lane = threadIdx.x & 63;
  const long row = (long)blockIdx.x*4 + (threadIdx.x >> 6);
  float2 v  = ((const float2*)(xw + row*CC))[lane];
  float2 w1 = ((const float2*)a1)[lane];
  float2 w2 = ((const float2*)a2)[lane];
  float s1 = v.x*w1.x + v.y*w1.y;
  float s2 = v.x*w2.x + v.y*w2.y;
  #pragma unroll
  for (int off=32; off; off>>=1){
    s1 += __shfl_xor(s1, off);
    s2 += __shfl_xor(s2, off);
  }
  if (lane==0){ as_[row]=s1; ad_[row]=s2; }
}

// ---------------- CSR build (edge_index identical for both layers)
__global__ void zero_int(int* __restrict__ p, int n){
  int i = blockIdx.x*256 + threadIdx.x;
  if (i < n) p[i] = 0;
}
__global__ void csr_hist(const int* __restrict__ ei, int* __restrict__ deg, int E){
  int e = blockIdx.x*256 + threadIdx.x;
  if (e < E) atomicAdd(&deg[ei[E + e]], 1);
}
__global__ __launch_bounds__(256) void csr_scan(const int* __restrict__ deg,
                                                int* __restrict__ rowptr,
                                                int* __restrict__ cursor, int N){
  __shared__ int part[257];
  const int t = threadIdx.x;
  const int per = N / 256;
  const int base = t*per;
  int s = 0;
  for (int j=0;j<per;j++) s += deg[base+j];
  part[t+1] = s;
  if (t==0) part[0] = 0;
  __syncthreads();
  if (t==0){
    for (int i=1;i<=256;i++) part[i] += part[i-1];
  }
  __syncthreads();
  int run = part[t];
  for (int j=0;j<per;j++){
    rowptr[base+j] = run;
    cursor[base+j] = run;
    run += deg[base+j];
  }
  if (t==255) rowptr[N] = run;
}
__global__ void csr_fill(const int* __restrict__ ei, int* __restrict__ cursor,
                         int* __restrict__ csrc, int E){
  int e = blockIdx.x*256 + threadIdx.x;
  if (e < E){
    int d = ei[E + e];
    int slot = atomicAdd(&cursor[d], 1);
    csrc[slot] = ei[e];
  }
}

// ---------------- fused GAT: online segment-softmax + aggregate (no atomics)
__global__ __launch_bounds__(256) void gat_gather(
    const int* __restrict__ rowptr, const int* __restrict__ csrc,
    const float* __restrict__ as_, const float* __restrict__ ad_,
    const float* __restrict__ xw, const float* __restrict__ b,
    float* __restrict__ out, int N){
  const int lane = threadIdx.x & 63;
  const int dst = blockIdx.x*4 + (threadIdx.x >> 6);
  const float adv = ad_[dst];
  float m = lrelu(as_[dst] + adv);
  float l = 1.f;
  float2 acc = ((const float2*)(xw + (size_t)dst*CC))[lane];
  const int kb = rowptr[dst], ke = rowptr[dst+1];
  int k = kb;
  int s_cur = 0; float a_cur = 0.f;
  if (k < ke){ s_cur = csrc[k]; a_cur = as_[s_cur]; }
  while (k < ke){
    int k1 = k + 1;
    int s_nxt = 0; float a_nxt = 0.f;
    if (k1 < ke){ s_nxt = csrc[k1]; a_nxt = as_[s_nxt]; }
    float2 v = ((const float2*)(xw + (size_t)s_cur*CC))[lane];
    float e = lrelu(a_cur + adv);
    float mn = fmaxf(m, e);
    float fr = __expf(m - mn);
    float p  = __expf(e - mn);
    acc.x = acc.x*fr + p*v.x;
    acc.y = acc.y*fr + p*v.y;
    l = l*fr + p;
    m = mn;
    s_cur = s_nxt; a_cur = a_nxt; k = k1;
  }
  float inv = 1.f / l;
  float2 bb = ((const float2*)b)[lane];
  float2 r; r.x = acc.x*inv + bb.x; r.y = acc.y*inv + bb.y;
  ((float2*)(out + (size_t)dst*CC))[lane] = r;
}

// ---------------- h (f32) -> IMG: per 64-key tile, 2048 uint4 of MFMA A-fragments
// u in [0,1024):  S-part:  u=(kt*8+ks)*64+l  -> H[key=64t+32kt+(l&31)][ks*16+(l>>5)*8+j]
// u in [1024,2048): PV-part: v=u-1024=(ct*4+ks)*64+l -> H[key=64t+ks*16+(l>>5)*8+j][ct*32+(l&31)]
__global__ __launch_bounds__(256) void convert_pack(const float* __restrict__ h,
                                                    uint4* __restrict__ IMG, int N){
  int idx = blockIdx.x*256 + threadIdx.x;
  int tile = idx >> 11;
  int u = idx & 2047;
  int l = u & 63, hh = l >> 5, l31 = l & 31;
  unsigned short o[8];
  if (u < 1024){
    int kt = u >> 9, ks = (u >> 6) & 7;
    int key = tile*64 + kt*32 + l31;
    const float* src = h + (size_t)key*CC + ks*16 + hh*8;
    #pragma unroll
    for (int j=0;j<8;j++) o[j] = f2bf(src[j]);
  } else {
    int v = u - 1024;
    int ct = v >> 8, ks = (v >> 6) & 3;
    int c = ct*32 + l31;
    int key0 = tile*64 + ks*16 + hh*8;
    #pragma unroll
    for (int j=0;j<8;j++) o[j] = f2bf(h[(size_t)(key0+j)*CC + c]);
  }
  IMG[idx] = *(uint4*)o;
}

#if defined(__has_builtin)
#if __has_builtin(__builtin_amdgcn_global_load_lds)
#define HAVE_GLL 1
#endif
#endif

#ifdef HAVE_GLL
static __device__ __forceinline__ void gload_lds16(const uint4* g, uint4* l){
  __builtin_amdgcn_global_load_lds(
      (const __attribute__((address_space(1))) unsigned int*)(const void*)g,
      (__attribute__((address_space(3))) unsigned int*)(void*)l, 16, 0, 0);
}
#endif

// ---------------- MFMA flash attention (bf16, 32x32x16), dbuf gload_lds staging,
// in-register P transpose (shfl_xor 32), defer-max, exp2 domain, KV-split
__global__ __launch_bounds__(256,2) void attn_mfma(
    const unsigned short* __restrict__ Qb, const uint4* __restrict__ IMG,
    unsigned short* __restrict__ opW, float* __restrict__ ml, int N, int nsplit){
  __shared__ uint4 SH[2*2048];      // double buffer, 32KB each

  const int tid = threadIdx.x;
  const int lane = tid & 63, w = tid >> 6;
  const int h = lane >> 5, q31 = lane & 31;
  const int qb0 = blockIdx.x * 128;
  const int split = blockIdx.y;
  const int ntt = N >> 6;
  const int tb = (ntt*split)/nsplit, te = (ntt*(split+1))/nsplit;

  // Q B-frags: qf[ks] = Qb[q][ks*16 + h*8 .. +7]  (Qb pre-scaled by QSCALE)
  bf16x8 qf[8];
  const int qrow = qb0 + w*32 + q31;
  #pragma unroll
  for (int ks=0; ks<8; ks++)
    qf[ks] = *(const bf16x8*)&Qb[(size_t)qrow*CC + ks*16 + h*8];

  f32x16 acc_o[4] = {};
  float m_ = -3.0e38f, l_ = 0.f;

  int cur = 0;
  // prologue stage tile tb into buf 0
  {
    const uint4* src = IMG + (size_t)tb*2048;
#ifdef HAVE_GLL
    #pragma unroll
    for (int i=0;i<8;i++){
      int u = i*256 + w*64;
      gload_lds16(src + u + lane, &SH[u]);
    }
#else
    #pragma unroll
    for (int i=0;i<8;i++){ int u = i*256 + tid; SH[u] = src[u]; }
#endif
  }

  for (int t=tb; t<te; t++){
    __syncthreads();                 // drains staging loads; aligns waves
    if (t+1 < te){
      const uint4* src = IMG + (size_t)(t+1)*2048;
      uint4* dst = &SH[(cur^1)*2048];
#ifdef HAVE_GLL
      #pragma unroll
      for (int i=0;i<8;i++){
        int u = i*256 + w*64;
        gload_lds16(src + u + lane, dst + u);
      }
#else
      #pragma unroll
      for (int i=0;i<8;i++){ int u = i*256 + tid; dst[u] = src[u]; }
#endif
    }
    const uint4* B = &SH[cur*2048];

    // ---- S phase: accs[kt] = S^T (32 keys x 32 q), rows=keys, cols=q
    f32x16 accs[2];
    #pragma unroll
    for (int kt=0; kt<2; kt++){
      f32x16 a = {};
      __builtin_amdgcn_s_setprio(1);
      #pragma unroll
      for (int ks=0; ks<8; ks++){
        bf16x8 hf = *(const bf16x8*)&B[(kt*8+ks)*64 + lane];
        a = __builtin_amdgcn_mfma_f32_32x32x16_bf16(hf, qf[ks], a, 0,0,0);
      }
      __builtin_amdgcn_s_setprio(0);
      accs[kt] = a;
    }

    // ---- online softmax (exp2 domain), defer-max
    float tm = accs[0][0];
    #pragma unroll
    for (int r=1;r<16;r++) tm = fmaxf(tm, accs[0][r]);
    #pragma unroll
    for (int r=0;r<16;r++) tm = fmaxf(tm, accs[1][r]);
    tm = fmaxf(tm, __shfl_xor(tm, 32));
    if (!__all(tm <= m_ + 11.0f)){
      float mn = fmaxf(m_, tm);
      float fr = __builtin_amdgcn_exp2f(m_ - mn);
      m_ = mn; l_ *= fr;
      #pragma unroll
      for (int ct=0; ct<4; ct++)
        #pragma unroll
        for (int r=0;r<16;r++) acc_o[ct][r] *= fr;
    }
    float ps = 0.f;
    #pragma unroll
    for (int kt=0; kt<2; kt++)
      #pragma unroll
      for (int r=0;r<16;r++){
        float p = __builtin_amdgcn_exp2f(accs[kt][r] - m_);
        accs[kt][r] = p; ps += p;
      }
    ps += __shfl_xor(ps, 32);
    l_ += ps;

    // ---- pack P to bf16 words: pk[kt][w] = keys (2w, 2w+1) rows (+4h)
    unsigned pk[2][8];
    #pragma unroll
    for (int kt=0; kt<2; kt++)
      #pragma unroll
      for (int wd=0; wd<8; wd++)
        pk[kt][wd] = packbf(accs[kt][2*wd], accs[kt][2*wd+1]);

    // ---- PV: in-register P^T frag assembly (half-exchange) + MFMA
    #pragma unroll
    for (int ks=0; ks<4; ks++){
      const int kt = ks >> 1, W = (ks & 1)*4;
      unsigned w0o = pk[kt][W+0], w1o = pk[kt][W+1];
      unsigned w2o = pk[kt][W+2], w3o = pk[kt][W+3];
      unsigned va = h ? w0o : w2o;       // h=1 sends W+0, h=0 sends W+2
      unsigned vb = h ? w1o : w3o;
      unsigned fa = (unsigned)__shfl_xor((int)va, 32);
      unsigned fb = (unsigned)__shfl_xor((int)vb, 32);
      uint4 fw;
      fw.x = h ? fa : w0o;
      fw.y = h ? fb : w1o;
      fw.z = h ? w2o : fa;
      fw.w = h ? w3o : fb;
      bf16x8 pfrag;
      __builtin_memcpy(&pfrag, &fw, 16);
      __builtin_amdgcn_s_setprio(1);
      #pragma unroll
      for (int ct=0; ct<4; ct++){
        bf16x8 hf = *(const bf16x8*)&B[1024 + (ct*4+ks)*64 + lane];
        acc_o[ct] = __builtin_amdgcn_mfma_f32_32x32x16_bf16(hf, pfrag, acc_o[ct], 0,0,0);
      }
      __builtin_amdgcn_s_setprio(0);
    }
    cur ^= 1;
  }

  // ---- epilogue: normalize, shfl-transpose halves, contiguous 128B/lane stores
  float inv = 1.f / l_;
  unsigned apk[4][8];
  #pragma unroll
  for (int ct=0; ct<4; ct++)
    #pragma unroll
    for (int wd=0; wd<8; wd++)
      apk[ct][wd] = packbf(acc_o[ct][2*wd]*inv, acc_o[ct][2*wd+1]*inv);

  unsigned short* orow = opW + (size_t)split*N*CC + (size_t)qrow*CC + h*64;
  #pragma unroll
  for (int cp=0; cp<2; cp++){
    #pragma unroll
    for (int jp=0; jp<4; jp++){
      int wd0 = 2*jp, wd1 = 2*jp+1;
      unsigned a0 = apk[cp][wd0],   a1 = apk[cp][wd1];
      unsigned b0 = apk[cp+2][wd0], b1 = apk[cp+2][wd1];
      unsigned v0 = h ? a0 : b0;       // h=1 sends ct(cp), h=0 sends ct(cp+2)
      unsigned v1 = h ? a1 : b1;
      unsigned f0 = (unsigned)__shfl_xor((int)v0, 32);
      unsigned f1 = (unsigned)__shfl_xor((int)v1, 32);
      unsigned o0 = h ? b0 : a0;       // own half
      unsigned o1 = h ? b1 : a1;
      uint4 st;
      st.x = h ? f0 : o0;
      st.y = h ? f1 : o1;
      st.z = h ? o0 : f0;
      st.w = h ? o1 : f1;
      *(uint4*)&orow[cp*32 + jp*8] = st;
    }
  }
  if (lane < 32)
    ((float2*)ml)[(size_t)split*N + qrow] = make_float2(m_, l_);
}

// ---------------- merge partials + att_bias + residual + LayerNorm (exp2 domain)
template<int NS>
__global__ __launch_bounds__(256) void merge_ln(
    const unsigned short* __restrict__ opW, const float* __restrict__ ml,
    const float* __restrict__ x, const float* __restrict__ ab,
    const float* __restrict__ gam, const float* __restrict__ bet,
    float* __restrict__ out, int N){
  const int lane = threadIdx.x & 63;
  const long row = (long)blockIdx.x*4 + (threadIdx.x >> 6);
  float mm[NS], ll[NS];
  float M = -3.0e38f;
  #pragma unroll
  for (int i=0;i<NS;i++){
    float2 v = ((const float2*)ml)[(size_t)i*N + row];
    mm[i]=v.x; ll[i]=v.y;
    M = fmaxf(M, v.x);
  }
  float den = 0.f;
  float wgt[NS];
  #pragma unroll
  for (int i=0;i<NS;i++){ wgt[i] = exp2f(mm[i]-M)*ll[i]; den += wgt[i]; }
  float invd = 1.f/den;
  float o0 = 0.f, o1 = 0.f;
  #pragma unroll
  for (int i=0;i<NS;i++){
    unsigned u = *(const unsigned*)&opW[((size_t)i*N + row)*CC + lane*2];
    float c = wgt[i]*invd;
    o0 += c * bf2f((unsigned short)(u & 0xffffu));
    o1 += c * bf2f((unsigned short)(u >> 16));
  }
  float2 xb = ((const float2*)(x + row*CC))[lane];
  float2 bb = ((const float2*)ab)[lane];
  float a0 = o0 + bb.x + xb.x;
  float a1 = o1 + bb.y + xb.y;
  float s = a0 + a1, ss = a0*a0 + a1*a1;
  #pragma unroll
  for (int off=32; off; off>>=1){ s += __shfl_xor(s,off); ss += __shfl_xor(ss,off); }
  float mu  = s * (1.f/128.f);
  float var = ss * (1.f/128.f) - mu*mu;
  float rstd = rsqrtf(var + 1e-5f);
  float2 gg = ((const float2*)gam)[lane];
  float2 b2 = ((const float2*)bet)[lane];
  float2 r;
  r.x = (a0 - mu)*rstd*gg.x + b2.x;
  r.y = (a1 - mu)*rstd*gg.y + b2.y;
  ((float2*)(out + row*CC))[lane] = r;
}

extern "C" void kernel_launch(void* const* d_in, const int* in_sizes, int n_in,
                              void* d_out, int out_size, void* d_ws, size_t ws_size,
                              hipStream_t stream) {
  const float* x   = (const float*)d_in[0];
  const int*   ei  = (const int*)d_in[1];
  const float* W1  = (const float*)d_in[3];
  const float* a_s1= (const float*)d_in[4];
  const float* a_d1= (const float*)d_in[5];
  const float* b1  = (const float*)d_in[6];
  const float* W2  = (const float*)d_in[7];
  const float* a_s2= (const float*)d_in[8];
  const float* a_d2= (const float*)d_in[9];
  const float* b2  = (const float*)d_in[10];
  const float* Wa  = (const float*)d_in[11];
  const float* ab  = (const float*)d_in[12];
  const float* g   = (const float*)d_in[13];
  const float* be  = (const float*)d_in[14];
  float* out = (float*)d_out;

  const int N = in_sizes[0] / CC;
  const int E = in_sizes[1] / 2;
  const size_t MB = 1024*1024;
  const size_t KB = 1024;

  char* base = (char*)d_ws;
  // GAT phase:  [0,8M) xw f32 | [8,16M) h f32 | [16,18M) csrc | [18M..) csr meta + as/ad
  // attn phase: [0,8M) IMG (fragment image) | [8,24M) opW (ns=4 x 4MB) | [24M..) ml
  //             Qb bf16 lives in d_out (dead before merge_ln writes out)
  float* xw   = (float*)(base + 0);
  float* h    = (float*)(base + 8*MB);
  int* csrc   = (int*)(base + 16*MB);
  int* rowptr = (int*)(base + 18*MB);
  int* cursor = (int*)(base + 18*MB + 128*KB);
  int* deg    = (int*)(base + 18*MB + 256*KB);
  float* as_  = (float*)(base + 18*MB + 384*KB);
  float* ad_  = (float*)(base + 18*MB + 512*KB);
  uint4* IMG  = (uint4*)(base + 0);
  unsigned short* opW = (unsigned short*)(base + 8*MB);
  float* ml   = (float*)(base + 24*MB);
  unsigned short* QbD = (unsigned short*)d_out;

  const int ns = 4;   // grid 512 = exactly 2 blocks/CU

  dim3 B(256);

  // ---- CSR build (shared by both GAT layers)
  zero_int<<<(N+255)/256, B, 0, stream>>>(deg, N);
  csr_hist<<<(E+255)/256, B, 0, stream>>>(ei, deg, E);
  csr_scan<<<1, B, 0, stream>>>(deg, rowptr, cursor, N);
  csr_fill<<<(E+255)/256, B, 0, stream>>>(ei, cursor, csrc, E);

  // ---- GAT layer 1
  gemm128<false,false><<<N/32, B, 0, stream>>>(x, W1, xw);
  rowdot2<<<N/4, B, 0, stream>>>(xw, a_s1, a_d1, as_, ad_);
  gat_gather<<<N/4, B, 0, stream>>>(rowptr, csrc, as_, ad_, xw, b1, h, N);

  // ---- GAT layer 2 (relu fused into gemm)
  gemm128<true,false><<<N/32, B, 0, stream>>>(h, W2, xw);
  rowdot2<<<N/4, B, 0, stream>>>(xw, a_s2, a_d2, as_, ad_);
  gat_gather<<<N/4, B, 0, stream>>>(rowptr, csrc, as_, ad_, xw, b2, h, N);

  // ---- temporal attention (bf16 MFMA 32x32 flash)
  gemm128<false,true><<<N/32, B, 0, stream>>>(h, Wa, QbD);     // q bf16 (pre-scaled)
  convert_pack<<<(N*32)/256, B, 0, stream>>>(h, IMG, N);       // h -> fragment image
  attn_mfma<<<dim3(N/128, ns), B, 0, stream>>>(QbD, IMG, opW, ml, N, ns);

  // ---- merge + att_bias + residual + LayerNorm
  merge_ln<4><<<N/4, B, 0, stream>>>(opW, ml, x, ab, g, be, out, N);
}

// Round 6
// 406.033 us; speedup vs baseline: 1.7393x; 1.1310x over previous
//
#include <hip/hip_runtime.h>

#define CC 128

typedef __attribute__((ext_vector_type(8))) short bf16x8;
typedef __attribute__((ext_vector_type(4))) float f32x4;
typedef __attribute__((ext_vector_type(16))) float f32x16;

static __device__ __forceinline__ float lrelu(float v){ return v > 0.f ? v : 0.2f*v; }
static __device__ __forceinline__ unsigned short f2bf(float f){
  unsigned u = __float_as_uint(f);
  unsigned r = (u + 0x7fffu + ((u >> 16) & 1u)) >> 16;
  return (unsigned short)r;
}
static __device__ __forceinline__ float bf2f(unsigned short s){
  return __uint_as_float(((unsigned)s) << 16);
}
// packed f32x2 -> bf16x2 (RNE), single VALU op
static __device__ __forceinline__ unsigned cvtpk(float lo, float hi){
  unsigned r;
  asm("v_cvt_pk_bf16_f32 %0, %1, %2" : "=v"(r) : "v"(lo), "v"(hi));
  return r;
}

// Q pre-scale: 1/sqrt(128) * log2(e)  (softmax runs in exp2 domain)
#define QSCALE (0.08838834764831845f * 1.4426950408889634f)

#if defined(__has_builtin)
#if __has_builtin(__builtin_amdgcn_global_load_lds)
#define HAVE_GLL 1
#endif
#endif

#ifdef HAVE_GLL
static __device__ __forceinline__ void gload_lds16(const uint4* g, uint4* l){
  __builtin_amdgcn_global_load_lds(
      (const __attribute__((address_space(1))) unsigned int*)(const void*)g,
      (__attribute__((address_space(3))) unsigned int*)(void*)l, 16, 0, 0);
}
#endif

// ---------------- pack 3 weight matrices into MFMA B-fragment images
// unit u: k=u>>8, ct=(u>>6)&3, l=u&63, h=l>>5, c=ct*32+(l&31)
// img[u] = bf16x8 of W[k*16+h*8+j][c], j=0..7
__global__ __launch_bounds__(256) void pack_w3(const float* __restrict__ W1,
                                               const float* __restrict__ W2,
                                               const float* __restrict__ Wa,
                                               unsigned short* __restrict__ img){
  int gid = blockIdx.x*256 + threadIdx.x;     // 0..6143
  int m = gid >> 11, u = gid & 2047;
  const float* W = (m==0) ? W1 : (m==1) ? W2 : Wa;
  int k = u >> 8, ct = (u >> 6) & 3, l = u & 63;
  int h = l >> 5, c = ct*32 + (l & 31);
  int k0 = k*16 + h*8;
  float f[8];
  #pragma unroll
  for (int j=0;j<8;j++) f[j] = W[(k0+j)*CC + c];
  uint4 o;
  o.x = cvtpk(f[0],f[1]); o.y = cvtpk(f[2],f[3]);
  o.z = cvtpk(f[4],f[5]); o.w = cvtpk(f[6],f[7]);
  *(uint4*)&img[((size_t)m*2048 + u)*8] = o;
}

// ---------------- MFMA GEMM: out[N,128] = (RELU?relu(A):A)[N,128] @ W
// W given as fragment image (pack_w3). A loaded directly (f32 -> cvt_pk).
// OMODE 0: f32 out; 1: bf16 out scaled by QSCALE
template<bool RELU, int OMODE>
__global__ __launch_bounds__(256) void gemm_mfma(const float* __restrict__ A,
                                                 const uint4* __restrict__ Wimg,
                                                 void* __restrict__ outv){
  __shared__ uint4 WS[2048];
  const int tid = threadIdx.x, lane = tid & 63, w = tid >> 6;
  const int h = lane >> 5, l31 = lane & 31;
  const long r0 = (long)blockIdx.x * 64;
#ifdef HAVE_GLL
  #pragma unroll
  for (int i=0;i<8;i++){ int u = i*256 + w*64; gload_lds16(Wimg + u + lane, &WS[u]); }
#else
  #pragma unroll
  for (int i=0;i<8;i++){ int u = i*256 + tid; WS[u] = Wimg[u]; }
#endif
  const int rt = w & 1, ct0 = (w >> 1) * 2;
  const float* arow = A + (r0 + rt*32 + l31)*CC + h*8;
  f32x16 acc0 = {}, acc1 = {};
  __syncthreads();
  #pragma unroll
  for (int k=0;k<8;k++){
    float4 a0 = *(const float4*)(arow + k*16);
    float4 a1 = *(const float4*)(arow + k*16 + 4);
    if (RELU){
      a0.x=fmaxf(a0.x,0.f); a0.y=fmaxf(a0.y,0.f); a0.z=fmaxf(a0.z,0.f); a0.w=fmaxf(a0.w,0.f);
      a1.x=fmaxf(a1.x,0.f); a1.y=fmaxf(a1.y,0.f); a1.z=fmaxf(a1.z,0.f); a1.w=fmaxf(a1.w,0.f);
    }
    uint4 av;
    av.x = cvtpk(a0.x,a0.y); av.y = cvtpk(a0.z,a0.w);
    av.z = cvtpk(a1.x,a1.y); av.w = cvtpk(a1.z,a1.w);
    bf16x8 afr; __builtin_memcpy(&afr, &av, 16);
    bf16x8 b0 = *(const bf16x8*)&WS[(k*4+ct0  )*64 + lane];
    bf16x8 b1 = *(const bf16x8*)&WS[(k*4+ct0+1)*64 + lane];
    acc0 = __builtin_amdgcn_mfma_f32_32x32x16_bf16(afr, b0, acc0, 0,0,0);
    acc1 = __builtin_amdgcn_mfma_f32_32x32x16_bf16(afr, b1, acc1, 0,0,0);
  }
  // C layout: col = l31 (+ct*32), row = (reg&3) + 8*(reg>>2) + 4*h (+rt*32)
  if (OMODE == 0){
    float* out = (float*)outv;
    #pragma unroll
    for (int r=0;r<16;r++){
      long row = r0 + rt*32 + (r&3) + 8*(r>>2) + 4*h;
      out[row*CC + ct0*32 + l31]      = acc0[r];
      out[row*CC + (ct0+1)*32 + l31]  = acc1[r];
    }
  } else {
    unsigned short* out = (unsigned short*)outv;
    #pragma unroll
    for (int r=0;r<16;r++){
      long row = r0 + rt*32 + (r&3) + 8*(r>>2) + 4*h;
      out[row*CC + ct0*32 + l31]      = f2bf(acc0[r]*QSCALE);
      out[row*CC + (ct0+1)*32 + l31]  = f2bf(acc1[r]*QSCALE);
    }
  }
}

// ---------------- per-row dot with two vectors
__global__ __launch_bounds__(256) void rowdot2(const float* __restrict__ xw,
                                               const float* __restrict__ a1,
                                               const float* __restrict__ a2,
                                               float* __restrict__ as_, float* __restrict__ ad_){
  const int lane = threadIdx.x & 63;
  const long row = (long)blockIdx.x*4 + (threadIdx.x >> 6);
  float2 v  = ((const float2*)(xw + row*CC))[lane];
  float2 w1 = ((const float2*)a1)[lane];
  float2 w2 = ((const float2*)a2)[lane];
  float s1 = v.x*w1.x + v.y*w1.y;
  float s2 = v.x*w2.x + v.y*w2.y;
  #pragma unroll
  for (int off=32; off; off>>=1){
    s1 += __shfl_xor(s1, off);
    s2 += __shfl_xor(s2, off);
  }
  if (lane==0){ as_[row]=s1; ad_[row]=s2; }
}

// ---------------- CSR build (edge_index identical for both layers)
__global__ void zero_int(int* __restrict__ p, int n){
  int i = blockIdx.x*256 + threadIdx.x;
  if (i < n) p[i] = 0;
}
__global__ void csr_hist(const int* __restrict__ ei, int* __restrict__ deg, int E){
  int e = blockIdx.x*256 + threadIdx.x;
  if (e < E) atomicAdd(&deg[ei[E + e]], 1);
}
__global__ __launch_bounds__(256) void csr_scan(const int* __restrict__ deg,
                                                int* __restrict__ rowptr,
                                                int* __restrict__ cursor, int N){
  __shared__ int part[257];
  const int t = threadIdx.x;
  const int per = N / 256;
  const int base = t*per;
  int s = 0;
  for (int j=0;j<per;j++) s += deg[base+j];
  part[t+1] = s;
  if (t==0) part[0] = 0;
  __syncthreads();
  if (t==0){
    for (int i=1;i<=256;i++) part[i] += part[i-1];
  }
  __syncthreads();
  int run = part[t];
  for (int j=0;j<per;j++){
    rowptr[base+j] = run;
    cursor[base+j] = run;
    run += deg[base+j];
  }
  if (t==255) rowptr[N] = run;
}
__global__ void csr_fill(const int* __restrict__ ei, int* __restrict__ cursor,
                         int* __restrict__ csrc, int E){
  int e = blockIdx.x*256 + threadIdx.x;
  if (e < E){
    int d = ei[E + e];
    int slot = atomicAdd(&cursor[d], 1);
    csrc[slot] = ei[e];
  }
}

// ---------------- fused GAT: online segment-softmax + aggregate (no atomics)
__global__ __launch_bounds__(256) void gat_gather(
    const int* __restrict__ rowptr, const int* __restrict__ csrc,
    const float* __restrict__ as_, const float* __restrict__ ad_,
    const float* __restrict__ xw, const float* __restrict__ b,
    float* __restrict__ out, int N){
  const int lane = threadIdx.x & 63;
  const int dst = blockIdx.x*4 + (threadIdx.x >> 6);
  const float adv = ad_[dst];
  float m = lrelu(as_[dst] + adv);
  float l = 1.f;
  float2 acc = ((const float2*)(xw + (size_t)dst*CC))[lane];
  const int kb = rowptr[dst], ke = rowptr[dst+1];
  int k = kb;
  int s_cur = 0; float a_cur = 0.f; float2 v_cur = make_float2(0.f,0.f);
  if (k < ke){
    s_cur = csrc[k]; a_cur = as_[s_cur];
    v_cur = ((const float2*)(xw + (size_t)s_cur*CC))[lane];
  }
  while (k < ke){
    int k1 = k + 1;
    int s_nxt = 0; float a_nxt = 0.f; float2 v_nxt = make_float2(0.f,0.f);
    if (k1 < ke){
      s_nxt = csrc[k1]; a_nxt = as_[s_nxt];
      v_nxt = ((const float2*)(xw + (size_t)s_nxt*CC))[lane];   // prefetch row
    }
    float e = lrelu(a_cur + adv);
    float mn = fmaxf(m, e);
    float fr = __expf(m - mn);
    float p  = __expf(e - mn);
    acc.x = acc.x*fr + p*v_cur.x;
    acc.y = acc.y*fr + p*v_cur.y;
    l = l*fr + p;
    m = mn;
    s_cur = s_nxt; a_cur = a_nxt; v_cur = v_nxt; k = k1;
  }
  float inv = 1.f / l;
  float2 bb = ((const float2*)b)[lane];
  float2 r; r.x = acc.x*inv + bb.x; r.y = acc.y*inv + bb.y;
  ((float2*)(out + (size_t)dst*CC))[lane] = r;
}

// ---------------- h (f32) -> IMG: per 64-key tile, 2048 uint4 of MFMA A-fragments
// u in [0,1024):  S-part:  u=(kt*8+ks)*64+l  -> H[key=64t+32kt+(l&31)][ks*16+(l>>5)*8+j]
// u in [1024,2048): PV-part: v=u-1024=(ct*4+ks)*64+l -> H[key=64t+ks*16+(l>>5)*8+j][ct*32+(l&31)]
__global__ __launch_bounds__(256) void convert_pack(const float* __restrict__ h,
                                                    uint4* __restrict__ IMG, int N){
  int idx = blockIdx.x*256 + threadIdx.x;
  int tile = idx >> 11;
  int u = idx & 2047;
  int l = u & 63, hh = l >> 5, l31 = l & 31;
  float f[8];
  if (u < 1024){
    int kt = u >> 9, ks = (u >> 6) & 7;
    int key = tile*64 + kt*32 + l31;
    const float* src = h + (size_t)key*CC + ks*16 + hh*8;
    #pragma unroll
    for (int j=0;j<8;j++) f[j] = src[j];
  } else {
    int v = u - 1024;
    int ct = v >> 8, ks = (v >> 6) & 3;
    int c = ct*32 + l31;
    int key0 = tile*64 + ks*16 + hh*8;
    #pragma unroll
    for (int j=0;j<8;j++) f[j] = h[(size_t)(key0+j)*CC + c];
  }
  uint4 o;
  o.x = cvtpk(f[0],f[1]); o.y = cvtpk(f[2],f[3]);
  o.z = cvtpk(f[4],f[5]); o.w = cvtpk(f[6],f[7]);
  IMG[idx] = o;
}

// ---------------- MFMA flash attention (bf16, 32x32x16), dbuf gload_lds staging,
// in-register P transpose (shfl_xor 32), defer-max, exp2 domain, KV-split
__global__ __launch_bounds__(256,2) void attn_mfma(
    const unsigned short* __restrict__ Qb, const uint4* __restrict__ IMG,
    unsigned short* __restrict__ opW, float* __restrict__ ml, int N, int nsplit){
  __shared__ uint4 SH[2*2048];      // double buffer, 32KB each

  const int tid = threadIdx.x;
  const int lane = tid & 63, w = tid >> 6;
  const int h = lane >> 5, q31 = lane & 31;
  const int qb0 = blockIdx.x * 128;
  const int split = blockIdx.y;
  const int ntt = N >> 6;
  const int tb = (ntt*split)/nsplit, te = (ntt*(split+1))/nsplit;

  // Q B-frags: qf[ks] = Qb[q][ks*16 + h*8 .. +7]  (Qb pre-scaled by QSCALE)
  bf16x8 qf[8];
  const int qrow = qb0 + w*32 + q31;
  #pragma unroll
  for (int ks=0; ks<8; ks++)
    qf[ks] = *(const bf16x8*)&Qb[(size_t)qrow*CC + ks*16 + h*8];

  f32x16 acc_o[4] = {};
  float m_ = -3.0e38f, l_ = 0.f;

  int cur = 0;
  {
    const uint4* src = IMG + (size_t)tb*2048;
#ifdef HAVE_GLL
    #pragma unroll
    for (int i=0;i<8;i++){ int u = i*256 + w*64; gload_lds16(src + u + lane, &SH[u]); }
#else
    #pragma unroll
    for (int i=0;i<8;i++){ int u = i*256 + tid; SH[u] = src[u]; }
#endif
  }

  for (int t=tb; t<te; t++){
    __syncthreads();                 // drains staging loads; aligns waves
    if (t+1 < te){
      const uint4* src = IMG + (size_t)(t+1)*2048;
      uint4* dst = &SH[(cur^1)*2048];
#ifdef HAVE_GLL
      #pragma unroll
      for (int i=0;i<8;i++){ int u = i*256 + w*64; gload_lds16(src + u + lane, dst + u); }
#else
      #pragma unroll
      for (int i=0;i<8;i++){ int u = i*256 + tid; dst[u] = src[u]; }
#endif
    }
    const uint4* B = &SH[cur*2048];

    // ---- S phase: accs[kt] = S^T (32 keys x 32 q)
    f32x16 accs[2];
    #pragma unroll
    for (int kt=0; kt<2; kt++){
      f32x16 a = {};
      __builtin_amdgcn_s_setprio(1);
      #pragma unroll
      for (int ks=0; ks<8; ks++){
        bf16x8 hf = *(const bf16x8*)&B[(kt*8+ks)*64 + lane];
        a = __builtin_amdgcn_mfma_f32_32x32x16_bf16(hf, qf[ks], a, 0,0,0);
      }
      __builtin_amdgcn_s_setprio(0);
      accs[kt] = a;
    }

    // ---- online softmax (exp2 domain), defer-max; tree reductions
    float tmax[16];
    #pragma unroll
    for (int r=0;r<16;r++) tmax[r] = fmaxf(accs[0][r], accs[1][r]);
    #pragma unroll
    for (int s=8; s; s>>=1)
      #pragma unroll
      for (int r=0;r<s;r++) tmax[r] = fmaxf(tmax[r], tmax[r+s]);
    float tm = fmaxf(tmax[0], __shfl_xor(tmax[0], 32));
    if (!__all(tm <= m_ + 11.0f)){
      float mn = fmaxf(m_, tm);
      float fr = __builtin_amdgcn_exp2f(m_ - mn);
      m_ = mn; l_ *= fr;
      #pragma unroll
      for (int ct=0; ct<4; ct++)
        #pragma unroll
        for (int r=0;r<16;r++) acc_o[ct][r] *= fr;
    }
    float psum[16];
    #pragma unroll
    for (int kt=0; kt<2; kt++)
      #pragma unroll
      for (int r=0;r<16;r++)
        accs[kt][r] = __builtin_amdgcn_exp2f(accs[kt][r] - m_);
    #pragma unroll
    for (int r=0;r<16;r++) psum[r] = accs[0][r] + accs[1][r];
    #pragma unroll
    for (int s=8; s; s>>=1)
      #pragma unroll
      for (int r=0;r<s;r++) psum[r] += psum[r+s];
    l_ += psum[0] + __shfl_xor(psum[0], 32);

    // ---- pack P to bf16 words (v_cvt_pk): pk[kt][wd] = keys (2wd, 2wd+1)
    unsigned pk[2][8];
    #pragma unroll
    for (int kt=0; kt<2; kt++)
      #pragma unroll
      for (int wd=0; wd<8; wd++)
        pk[kt][wd] = cvtpk(accs[kt][2*wd], accs[kt][2*wd+1]);

    // ---- PV: in-register P^T frag assembly (half-exchange) + MFMA
    #pragma unroll
    for (int ks=0; ks<4; ks++){
      const int kt = ks >> 1, W = (ks & 1)*4;
      unsigned w0o = pk[kt][W+0], w1o = pk[kt][W+1];
      unsigned w2o = pk[kt][W+2], w3o = pk[kt][W+3];
      unsigned va = h ? w0o : w2o;
      unsigned vb = h ? w1o : w3o;
      unsigned fa = (unsigned)__shfl_xor((int)va, 32);
      unsigned fb = (unsigned)__shfl_xor((int)vb, 32);
      uint4 fw;
      fw.x = h ? fa : w0o;
      fw.y = h ? fb : w1o;
      fw.z = h ? w2o : fa;
      fw.w = h ? w3o : fb;
      bf16x8 pfrag;
      __builtin_memcpy(&pfrag, &fw, 16);
      __builtin_amdgcn_s_setprio(1);
      #pragma unroll
      for (int ct=0; ct<4; ct++){
        bf16x8 hf = *(const bf16x8*)&B[1024 + (ct*4+ks)*64 + lane];
        acc_o[ct] = __builtin_amdgcn_mfma_f32_32x32x16_bf16(hf, pfrag, acc_o[ct], 0,0,0);
      }
      __builtin_amdgcn_s_setprio(0);
    }
    cur ^= 1;
  }

  // ---- epilogue: normalize, shfl-transpose halves, contiguous 128B/lane stores
  float inv = 1.f / l_;
  unsigned apk[4][8];
  #pragma unroll
  for (int ct=0; ct<4; ct++)
    #pragma unroll
    for (int wd=0; wd<8; wd++)
      apk[ct][wd] = cvtpk(acc_o[ct][2*wd]*inv, acc_o[ct][2*wd+1]*inv);

  unsigned short* orow = opW + (size_t)split*N*CC + (size_t)qrow*CC + h*64;
  #pragma unroll
  for (int cp=0; cp<2; cp++){
    #pragma unroll
    for (int jp=0; jp<4; jp++){
      int wd0 = 2*jp, wd1 = 2*jp+1;
      unsigned a0 = apk[cp][wd0],   a1 = apk[cp][wd1];
      unsigned b0 = apk[cp+2][wd0], b1 = apk[cp+2][wd1];
      unsigned v0 = h ? a0 : b0;
      unsigned v1 = h ? a1 : b1;
      unsigned f0 = (unsigned)__shfl_xor((int)v0, 32);
      unsigned f1 = (unsigned)__shfl_xor((int)v1, 32);
      unsigned o0 = h ? b0 : a0;
      unsigned o1 = h ? b1 : a1;
      uint4 st;
      st.x = h ? f0 : o0;
      st.y = h ? f1 : o1;
      st.z = h ? o0 : f0;
      st.w = h ? o1 : f1;
      *(uint4*)&orow[cp*32 + jp*8] = st;
    }
  }
  if (lane < 32)
    ((float2*)ml)[(size_t)split*N + qrow] = make_float2(m_, l_);
}

// ---------------- merge partials + att_bias + residual + LayerNorm (exp2 domain)
template<int NS>
__global__ __launch_bounds__(256) void merge_ln(
    const unsigned short* __restrict__ opW, const float* __restrict__ ml,
    const float* __restrict__ x, const float* __restrict__ ab,
    const float* __restrict__ gam, const float* __restrict__ bet,
    float* __restrict__ out, int N){
  const int lane = threadIdx.x & 63;
  const long row = (long)blockIdx.x*4 + (threadIdx.x >> 6);
  float mm[NS], ll[NS];
  float M = -3.0e38f;
  #pragma unroll
  for (int i=0;i<NS;i++){
    float2 v = ((const float2*)ml)[(size_t)i*N + row];
    mm[i]=v.x; ll[i]=v.y;
    M = fmaxf(M, v.x);
  }
  float den = 0.f;
  float wgt[NS];
  #pragma unroll
  for (int i=0;i<NS;i++){ wgt[i] = exp2f(mm[i]-M)*ll[i]; den += wgt[i]; }
  float invd = 1.f/den;
  float o0 = 0.f, o1 = 0.f;
  #pragma unroll
  for (int i=0;i<NS;i++){
    unsigned u = *(const unsigned*)&opW[((size_t)i*N + row)*CC + lane*2];
    float c = wgt[i]*invd;
    o0 += c * bf2f((unsigned short)(u & 0xffffu));
    o1 += c * bf2f((unsigned short)(u >> 16));
  }
  float2 xb = ((const float2*)(x + row*CC))[lane];
  float2 bb = ((const float2*)ab)[lane];
  float a0 = o0 + bb.x + xb.x;
  float a1 = o1 + bb.y + xb.y;
  float s = a0 + a1, ss = a0*a0 + a1*a1;
  #pragma unroll
  for (int off=32; off; off>>=1){ s += __shfl_xor(s,off); ss += __shfl_xor(ss,off); }
  float mu  = s * (1.f/128.f);
  float var = ss * (1.f/128.f) - mu*mu;
  float rstd = rsqrtf(var + 1e-5f);
  float2 gg = ((const float2*)gam)[lane];
  float2 b2 = ((const float2*)bet)[lane];
  float2 r;
  r.x = (a0 - mu)*rstd*gg.x + b2.x;
  r.y = (a1 - mu)*rstd*gg.y + b2.y;
  ((float2*)(out + row*CC))[lane] = r;
}

extern "C" void kernel_launch(void* const* d_in, const int* in_sizes, int n_in,
                              void* d_out, int out_size, void* d_ws, size_t ws_size,
                              hipStream_t stream) {
  const float* x   = (const float*)d_in[0];
  const int*   ei  = (const int*)d_in[1];
  const float* W1  = (const float*)d_in[3];
  const float* a_s1= (const float*)d_in[4];
  const float* a_d1= (const float*)d_in[5];
  const float* b1  = (const float*)d_in[6];
  const float* W2  = (const float*)d_in[7];
  const float* a_s2= (const float*)d_in[8];
  const float* a_d2= (const float*)d_in[9];
  const float* b2  = (const float*)d_in[10];
  const float* Wa  = (const float*)d_in[11];
  const float* ab  = (const float*)d_in[12];
  const float* g   = (const float*)d_in[13];
  const float* be  = (const float*)d_in[14];
  float* out = (float*)d_out;

  const int N = in_sizes[0] / CC;
  const int E = in_sizes[1] / 2;
  const size_t MB = 1024*1024;
  const size_t KB = 1024;

  char* base = (char*)d_ws;
  // GAT phase:  [0,8M) xw f32 | [8,16M) h f32 | [16,18M) csrc | [18M,18.7M) csr meta
  //             [19M,19.1M) Wimg (bf16 frag images, clobbered later by opW writes)
  // attn phase: [0,8M) IMG | [8,24M) opW (4 x 4MB) | [24M,24.5M) ml
  //             Qb bf16 lives in d_out (dead before merge_ln writes out)
  float* xw   = (float*)(base + 0);
  float* h    = (float*)(base + 8*MB);
  int* csrc   = (int*)(base + 16*MB);
  int* rowptr = (int*)(base + 18*MB);
  int* cursor = (int*)(base + 18*MB + 128*KB);
  int* deg    = (int*)(base + 18*MB + 256*KB);
  float* as_  = (float*)(base + 18*MB + 384*KB);
  float* ad_  = (float*)(base + 18*MB + 512*KB);
  unsigned short* Wimg = (unsigned short*)(base + 19*MB);
  uint4* IMG  = (uint4*)(base + 0);
  unsigned short* opW = (unsigned short*)(base + 8*MB);
  float* ml   = (float*)(base + 24*MB);
  unsigned short* QbD = (unsigned short*)d_out;

  const uint4* W1i = (const uint4*)(Wimg);
  const uint4* W2i = (const uint4*)(Wimg + 2048*8);
  const uint4* Wai = (const uint4*)(Wimg + 2*2048*8);

  const int ns = 4;   // grid 512 = exactly 2 blocks/CU
  dim3 B(256);

  // ---- weight fragment images + CSR build (both graph-invariant per launch)
  pack_w3<<<24, B, 0, stream>>>(W1, W2, Wa, Wimg);
  zero_int<<<(N+255)/256, B, 0, stream>>>(deg, N);
  csr_hist<<<(E+255)/256, B, 0, stream>>>(ei, deg, E);
  csr_scan<<<1, B, 0, stream>>>(deg, rowptr, cursor, N);
  csr_fill<<<(E+255)/256, B, 0, stream>>>(ei, cursor, csrc, E);

  // ---- GAT layer 1
  gemm_mfma<false,0><<<N/64, B, 0, stream>>>(x, W1i, xw);
  rowdot2<<<N/4, B, 0, stream>>>(xw, a_s1, a_d1, as_, ad_);
  gat_gather<<<N/4, B, 0, stream>>>(rowptr, csrc, as_, ad_, xw, b1, h, N);

  // ---- GAT layer 2 (relu fused into gemm A-load)
  gemm_mfma<true,0><<<N/64, B, 0, stream>>>(h, W2i, xw);
  rowdot2<<<N/4, B, 0, stream>>>(xw, a_s2, a_d2, as_, ad_);
  gat_gather<<<N/4, B, 0, stream>>>(rowptr, csrc, as_, ad_, xw, b2, h, N);

  // ---- temporal attention (bf16 MFMA 32x32 flash)
  gemm_mfma<false,1><<<N/64, B, 0, stream>>>(h, Wai, QbD);     // q bf16 (pre-scaled)
  convert_pack<<<(N*32)/256, B, 0, stream>>>(h, IMG, N);       // h -> fragment image
  attn_mfma<<<dim3(N/128, ns), B, 0, stream>>>(QbD, IMG, opW, ml, N, ns);

  // ---- merge + att_bias + residual + LayerNorm
  merge_ln<4><<<N/4, B, 0, stream>>>(opW, ml, x, ab, g, be, out, N);
}

// Round 7
// 332.452 us; speedup vs baseline: 2.1243x; 1.2213x over previous
//
#include <hip/hip_runtime.h>

#define CC 128

typedef __attribute__((ext_vector_type(8))) short bf16x8;
typedef __attribute__((ext_vector_type(16))) float f32x16;

static __device__ __forceinline__ float lrelu(float v){ return v > 0.f ? v : 0.2f*v; }
static __device__ __forceinline__ unsigned short f2bf(float f){
  unsigned u = __float_as_uint(f);
  unsigned r = (u + 0x7fffu + ((u >> 16) & 1u)) >> 16;
  return (unsigned short)r;
}
static __device__ __forceinline__ float bf2f(unsigned short s){
  return __uint_as_float(((unsigned)s) << 16);
}
static __device__ __forceinline__ unsigned cvtpk(float lo, float hi){
  unsigned r;
  asm("v_cvt_pk_bf16_f32 %0, %1, %2" : "=v"(r) : "v"(lo), "v"(hi));
  return r;
}

#define QSCALE (0.08838834764831845f * 1.4426950408889634f)
#define L2E 1.4426950408889634f

#if defined(__has_builtin)
#if __has_builtin(__builtin_amdgcn_global_load_lds)
#define HAVE_GLL 1
#endif
#endif

#ifdef HAVE_GLL
static __device__ __forceinline__ void gload_lds16(const uint4* g, uint4* l){
  __builtin_amdgcn_global_load_lds(
      (const __attribute__((address_space(1))) unsigned int*)(const void*)g,
      (__attribute__((address_space(3))) unsigned int*)(void*)l, 16, 0, 0);
}
#endif

// ---------------- pack 3 weight matrices into MFMA B-fragment images
__global__ __launch_bounds__(256) void pack_w3(const float* __restrict__ W1,
                                               const float* __restrict__ W2,
                                               const float* __restrict__ Wa,
                                               unsigned short* __restrict__ img){
  int gid = blockIdx.x*256 + threadIdx.x;     // 0..6143
  int m = gid >> 11, u = gid & 2047;
  const float* W = (m==0) ? W1 : (m==1) ? W2 : Wa;
  int k = u >> 8, ct = (u >> 6) & 3, l = u & 63;
  int h = l >> 5, c = ct*32 + (l & 31);
  int k0 = k*16 + h*8;
  float f[8];
  #pragma unroll
  for (int j=0;j<8;j++) f[j] = W[(k0+j)*CC + c];
  uint4 o;
  o.x = cvtpk(f[0],f[1]); o.y = cvtpk(f[2],f[3]);
  o.z = cvtpk(f[4],f[5]); o.w = cvtpk(f[6],f[7]);
  *(uint4*)&img[((size_t)m*2048 + u)*8] = o;
}

// ---------------- MFMA GEMM: out_bf16[N,128] = A[N,128] @ W ; A f32 or bf16
// OMODE 0: plain bf16 out; 1: bf16 out scaled by QSCALE
template<bool ABF16, int OMODE>
__global__ __launch_bounds__(256) void gemm_mfma(const void* __restrict__ Av,
                                                 const uint4* __restrict__ Wimg,
                                                 unsigned short* __restrict__ out){
  __shared__ uint4 WS[2048];
  const int tid = threadIdx.x, lane = tid & 63, w = tid >> 6;
  const int h = lane >> 5, l31 = lane & 31;
  const long r0 = (long)blockIdx.x * 64;
#ifdef HAVE_GLL
  #pragma unroll
  for (int i=0;i<8;i++){ int u = i*256 + w*64; gload_lds16(Wimg + u + lane, &WS[u]); }
#else
  #pragma unroll
  for (int i=0;i<8;i++){ int u = i*256 + tid; WS[u] = Wimg[u]; }
#endif
  const int rt = w & 1, ct0 = (w >> 1) * 2;
  const long arow = (r0 + rt*32 + l31)*CC + h*8;
  f32x16 acc0 = {}, acc1 = {};
  __syncthreads();
  #pragma unroll
  for (int k=0;k<8;k++){
    bf16x8 afr;
    if (ABF16){
      afr = *(const bf16x8*)&((const unsigned short*)Av)[arow + k*16];
    } else {
      const float* ap = (const float*)Av + arow + k*16;
      float4 a0 = *(const float4*)ap;
      float4 a1 = *(const float4*)(ap+4);
      uint4 av;
      av.x = cvtpk(a0.x,a0.y); av.y = cvtpk(a0.z,a0.w);
      av.z = cvtpk(a1.x,a1.y); av.w = cvtpk(a1.z,a1.w);
      __builtin_memcpy(&afr, &av, 16);
    }
    bf16x8 b0 = *(const bf16x8*)&WS[(k*4+ct0  )*64 + lane];
    bf16x8 b1 = *(const bf16x8*)&WS[(k*4+ct0+1)*64 + lane];
    acc0 = __builtin_amdgcn_mfma_f32_32x32x16_bf16(afr, b0, acc0, 0,0,0);
    acc1 = __builtin_amdgcn_mfma_f32_32x32x16_bf16(afr, b1, acc1, 0,0,0);
  }
  #pragma unroll
  for (int r=0;r<16;r++){
    long row = r0 + rt*32 + (r&3) + 8*(r>>2) + 4*h;
    float s0 = (OMODE==1) ? acc0[r]*QSCALE : acc0[r];
    float s1 = (OMODE==1) ? acc1[r]*QSCALE : acc1[r];
    out[row*CC + ct0*32 + l31]     = f2bf(s0);
    out[row*CC + (ct0+1)*32 + l31] = f2bf(s1);
  }
}

// ---------------- per-row dot with two vectors (bf16 rows)
__global__ __launch_bounds__(256) void rowdot2b(const unsigned short* __restrict__ X,
                                                const float* __restrict__ a1,
                                                const float* __restrict__ a2,
                                                float* __restrict__ as_, float* __restrict__ ad_){
  const int lane = threadIdx.x & 63;
  const long row = (long)blockIdx.x*4 + (threadIdx.x >> 6);
  unsigned u = *(const unsigned*)&X[row*CC + lane*2];
  float v0 = bf2f((unsigned short)(u & 0xffffu));
  float v1 = bf2f((unsigned short)(u >> 16));
  float2 w1 = ((const float2*)a1)[lane];
  float2 w2 = ((const float2*)a2)[lane];
  float s1 = v0*w1.x + v1*w1.y;
  float s2 = v0*w2.x + v1*w2.y;
  #pragma unroll
  for (int off=32; off; off>>=1){
    s1 += __shfl_xor(s1, off);
    s2 += __shfl_xor(s2, off);
  }
  if (lane==0){ as_[row]=s1; ad_[row]=s2; }
}

// ---------------- CSR build (edge_index identical for both layers)
__global__ void zero_int(int* __restrict__ p, int n){
  int i = blockIdx.x*256 + threadIdx.x;
  if (i < n) p[i] = 0;
}
__global__ void csr_hist(const int* __restrict__ ei, int* __restrict__ deg, int E){
  int e = blockIdx.x*256 + threadIdx.x;
  if (e < E) atomicAdd(&deg[ei[E + e]], 1);
}
__global__ __launch_bounds__(256) void csr_scan(const int* __restrict__ deg,
                                                int* __restrict__ rowptr,
                                                int* __restrict__ cursor, int N){
  __shared__ int part[257];
  const int t = threadIdx.x;
  const int per = N / 256;
  const int base = t*per;
  int s = 0;
  for (int j=0;j<per;j++) s += deg[base+j];
  part[t+1] = s;
  if (t==0) part[0] = 0;
  __syncthreads();
  if (t==0){
    for (int i=1;i<=256;i++) part[i] += part[i-1];
  }
  __syncthreads();
  int run = part[t];
  for (int j=0;j<per;j++){
    rowptr[base+j] = run;
    cursor[base+j] = run;
    run += deg[base+j];
  }
  if (t==255) rowptr[N] = run;
}
__global__ void csr_fill(const int* __restrict__ ei, int* __restrict__ cursor,
                         int* __restrict__ csrc, int E){
  int e = blockIdx.x*256 + threadIdx.x;
  if (e < E){
    int d = ei[E + e];
    int slot = atomicAdd(&cursor[d], 1);
    csrc[slot] = ei[e];
  }
}

// ---------------- fused GAT: lane-parallel segment softmax + weighted gather (bf16)
// one wave per dst; phase1: edges across lanes (wave-reduce m,l);
// phase2: 2 edges/iter, lanes 0-31 even edge / 32-63 odd edge, 4 ch each.
template<bool RELUOUT>
__global__ __launch_bounds__(256) void gat_gather(
    const int* __restrict__ rowptr, const int* __restrict__ csrc,
    const float* __restrict__ as_, const float* __restrict__ ad_,
    const unsigned short* __restrict__ X, const float* __restrict__ b,
    unsigned short* __restrict__ O, int N){
  const int lane = threadIdx.x & 63;
  const int half = lane >> 5, l32 = lane & 31;
  const int dst = blockIdx.x*4 + (threadIdx.x >> 6);
  const float adv = ad_[dst];
  float m = lrelu(as_[dst] + adv);       // self-loop
  float l = 1.f;
  float acc0=0.f, acc1=0.f, acc2=0.f, acc3=0.f;
  if (half == 0){
    ushort4 v = *(const ushort4*)&X[(size_t)dst*CC + l32*4];
    acc0 = bf2f(v.x); acc1 = bf2f(v.y); acc2 = bf2f(v.z); acc3 = bf2f(v.w);
  }
  const int kb = rowptr[dst];
  const int deg = rowptr[dst+1] - kb;
  for (int c0 = 0; c0 < deg; c0 += 64){
    const int nv = min(64, deg - c0);
    int src = dst; float e = -3.0e38f;
    if (lane < nv){
      src = csrc[kb + c0 + lane];
      e = lrelu(as_[src] + adv);
    }
    float cm = e;
    #pragma unroll
    for (int off=32; off; off>>=1) cm = fmaxf(cm, __shfl_xor(cm, off));
    if (cm > m){
      float fr = __builtin_amdgcn_exp2f((m - cm)*L2E);
      l *= fr; acc0 *= fr; acc1 *= fr; acc2 *= fr; acc3 *= fr;
      m = cm;
    }
    float p = __builtin_amdgcn_exp2f((e - m)*L2E);   // 0 for invalid lanes
    float cs = p;
    #pragma unroll
    for (int off=32; off; off>>=1) cs += __shfl_xor(cs, off);
    l += cs;
    for (int j = 0; j < nv; j += 2){
      float w0 = __shfl(p, j);
      float w1 = __shfl(p, (j+1)&63);
      w1 = (j+1 < nv) ? w1 : 0.f;
      int s0 = __shfl(src, j);
      int s1 = __shfl(src, (j+1)&63);
      float wgt = half ? w1 : w0;
      int s = half ? s1 : s0;
      ushort4 v = *(const ushort4*)&X[(size_t)s*CC + l32*4];
      acc0 += wgt*bf2f(v.x); acc1 += wgt*bf2f(v.y);
      acc2 += wgt*bf2f(v.z); acc3 += wgt*bf2f(v.w);
    }
  }
  acc0 += __shfl_xor(acc0, 32);
  acc1 += __shfl_xor(acc1, 32);
  acc2 += __shfl_xor(acc2, 32);
  acc3 += __shfl_xor(acc3, 32);
  if (half == 0){
    float inv = 1.f / l;
    float4 bb = *(const float4*)&b[l32*4];
    float r0 = acc0*inv + bb.x, r1 = acc1*inv + bb.y;
    float r2 = acc2*inv + bb.z, r3 = acc3*inv + bb.w;
    if (RELUOUT){
      r0=fmaxf(r0,0.f); r1=fmaxf(r1,0.f); r2=fmaxf(r2,0.f); r3=fmaxf(r3,0.f);
    }
    uint2 o; o.x = cvtpk(r0,r1); o.y = cvtpk(r2,r3);
    *(uint2*)&O[(size_t)dst*CC + l32*4] = o;
  }
}

// ---------------- h (bf16) -> IMG fragment image; per KVB-key tile: NKT*1024 uint4
// S-part  (u < NKT*512):  u=(kt*8+ks)*64+l -> H[tile*KVB+kt*32+(l&31)][ks*16+(l>>5)*8 ..+7]
// PV-part: v=u-NKT*512 = (ct*2NKT+ks)*64+l -> H[tile*KVB+ks*16+(l>>5)*8+j][ct*32+(l&31)]
template<int NKT>
__global__ __launch_bounds__(256) void convert_pack(const unsigned short* __restrict__ h,
                                                    uint4* __restrict__ IMG, int N){
  const int KVB = NKT*32;
  int idx = blockIdx.x*256 + threadIdx.x;
  int tile = idx / (NKT*1024);
  int u = idx - tile*(NKT*1024);
  int l = u & 63, hh = l >> 5, l31 = l & 31;
  if (u < NKT*512){
    int kt = u >> 9, ks = (u >> 6) & 7;
    int key = tile*KVB + kt*32 + l31;
    IMG[idx] = *(const uint4*)&h[(size_t)key*CC + ks*16 + hh*8];
  } else {
    int v = u - NKT*512;
    int ks = (v >> 6) & (2*NKT - 1);
    int ct = v >> (NKT==1 ? 7 : 8);
    int c = ct*32 + l31;
    int key0 = tile*KVB + ks*16 + hh*8;
    unsigned short o[8];
    #pragma unroll
    for (int j=0;j<8;j++) o[j] = h[(size_t)(key0+j)*CC + c];
    IMG[idx] = *(uint4*)o;
  }
}

// ---------------- MFMA flash attention (bf16, 32x32x16), template KV tile size
template<int NKT>
__global__ __launch_bounds__(256,2) void attn_mfma(
    const unsigned short* __restrict__ Qb, const uint4* __restrict__ IMG,
    unsigned short* __restrict__ opW, float* __restrict__ ml, int N, int nsplit){
  const int TILE4 = NKT*1024;
  __shared__ uint4 SH[2*NKT*1024];

  const int tid = threadIdx.x;
  const int lane = tid & 63, w = tid >> 6;
  const int h = lane >> 5, q31 = lane & 31;
  // XCD-pinning swizzle: split = flat % nsplit -> all blocks of a split on one XCD
  const int flat = blockIdx.x;
  const int split = flat % nsplit;
  const int qb0 = (flat / nsplit) * 128;
  const int KVB = NKT*32;
  const int ntt = N / KVB;
  const int tb = (ntt*split)/nsplit, te = (ntt*(split+1))/nsplit;

  bf16x8 qf[8];
  const int qrow = qb0 + w*32 + q31;
  #pragma unroll
  for (int ks=0; ks<8; ks++)
    qf[ks] = *(const bf16x8*)&Qb[(size_t)qrow*CC + ks*16 + h*8];

  f32x16 acc_o[4] = {};
  float m_ = -3.0e38f, l_ = 0.f;

  int cur = 0;
  {
    const uint4* src = IMG + (size_t)tb*TILE4;
#ifdef HAVE_GLL
    #pragma unroll
    for (int i=0;i<NKT*4;i++){ int u = i*256 + w*64; gload_lds16(src + u + lane, &SH[u]); }
#else
    #pragma unroll
    for (int i=0;i<NKT*4;i++){ int u = i*256 + tid; SH[u] = src[u]; }
#endif
  }

  for (int t=tb; t<te; t++){
    __syncthreads();
    if (t+1 < te){
      const uint4* src = IMG + (size_t)(t+1)*TILE4;
      uint4* dst = &SH[(cur^1)*TILE4];
#ifdef HAVE_GLL
      #pragma unroll
      for (int i=0;i<NKT*4;i++){ int u = i*256 + w*64; gload_lds16(src + u + lane, dst + u); }
#else
      #pragma unroll
      for (int i=0;i<NKT*4;i++){ int u = i*256 + tid; dst[u] = src[u]; }
#endif
    }
    const uint4* B = &SH[cur*TILE4];

    // ---- S phase
    f32x16 accs[NKT];
    #pragma unroll
    for (int kt=0; kt<NKT; kt++){
      f32x16 a = {};
      __builtin_amdgcn_s_setprio(1);
      #pragma unroll
      for (int ks=0; ks<8; ks++){
        bf16x8 hf = *(const bf16x8*)&B[(kt*8+ks)*64 + lane];
        a = __builtin_amdgcn_mfma_f32_32x32x16_bf16(hf, qf[ks], a, 0,0,0);
      }
      __builtin_amdgcn_s_setprio(0);
      accs[kt] = a;
    }

    // ---- online softmax (exp2 domain), defer-max; tree reductions
    float tmax[16];
    #pragma unroll
    for (int r=0;r<16;r++){
      float v = accs[0][r];
      if (NKT == 2) v = fmaxf(v, accs[1][r]);
      tmax[r] = v;
    }
    #pragma unroll
    for (int s=8; s; s>>=1)
      #pragma unroll
      for (int r=0;r<s;r++) tmax[r] = fmaxf(tmax[r], tmax[r+s]);
    float tm = fmaxf(tmax[0], __shfl_xor(tmax[0], 32));
    if (!__all(tm <= m_ + 11.0f)){
      float mn = fmaxf(m_, tm);
      float fr = __builtin_amdgcn_exp2f(m_ - mn);
      m_ = mn; l_ *= fr;
      #pragma unroll
      for (int ct=0; ct<4; ct++)
        #pragma unroll
        for (int r=0;r<16;r++) acc_o[ct][r] *= fr;
    }
    float psum[16];
    #pragma unroll
    for (int kt=0; kt<NKT; kt++)
      #pragma unroll
      for (int r=0;r<16;r++)
        accs[kt][r] = __builtin_amdgcn_exp2f(accs[kt][r] - m_);
    #pragma unroll
    for (int r=0;r<16;r++){
      float v = accs[0][r];
      if (NKT == 2) v += accs[1][r];
      psum[r] = v;
    }
    #pragma unroll
    for (int s=8; s; s>>=1)
      #pragma unroll
      for (int r=0;r<s;r++) psum[r] += psum[r+s];
    l_ += psum[0] + __shfl_xor(psum[0], 32);

    // ---- pack P to bf16 words
    unsigned pk[NKT][8];
    #pragma unroll
    for (int kt=0; kt<NKT; kt++)
      #pragma unroll
      for (int wd=0; wd<8; wd++)
        pk[kt][wd] = cvtpk(accs[kt][2*wd], accs[kt][2*wd+1]);

    // ---- PV: in-register P^T frag assembly (half-exchange) + MFMA
    #pragma unroll
    for (int ks=0; ks<2*NKT; ks++){
      const int kt = ks >> 1, W = (ks & 1)*4;
      unsigned w0o = pk[kt][W+0], w1o = pk[kt][W+1];
      unsigned w2o = pk[kt][W+2], w3o = pk[kt][W+3];
      unsigned va = h ? w0o : w2o;
      unsigned vb = h ? w1o : w3o;
      unsigned fa = (unsigned)__shfl_xor((int)va, 32);
      unsigned fb = (unsigned)__shfl_xor((int)vb, 32);
      uint4 fw;
      fw.x = h ? fa : w0o;
      fw.y = h ? fb : w1o;
      fw.z = h ? w2o : fa;
      fw.w = h ? w3o : fb;
      bf16x8 pfrag;
      __builtin_memcpy(&pfrag, &fw, 16);
      __builtin_amdgcn_s_setprio(1);
      #pragma unroll
      for (int ct=0; ct<4; ct++){
        bf16x8 hf = *(const bf16x8*)&B[NKT*512 + (ct*2*NKT+ks)*64 + lane];
        acc_o[ct] = __builtin_amdgcn_mfma_f32_32x32x16_bf16(hf, pfrag, acc_o[ct], 0,0,0);
      }
      __builtin_amdgcn_s_setprio(0);
    }
    cur ^= 1;
  }

  // ---- epilogue: normalize, shfl-transpose halves, contiguous stores
  float inv = 1.f / l_;
  unsigned apk[4][8];
  #pragma unroll
  for (int ct=0; ct<4; ct++)
    #pragma unroll
    for (int wd=0; wd<8; wd++)
      apk[ct][wd] = cvtpk(acc_o[ct][2*wd]*inv, acc_o[ct][2*wd+1]*inv);

  unsigned short* orow = opW + (size_t)split*N*CC + (size_t)qrow*CC + h*64;
  #pragma unroll
  for (int cp=0; cp<2; cp++){
    #pragma unroll
    for (int jp=0; jp<4; jp++){
      int wd0 = 2*jp, wd1 = 2*jp+1;
      unsigned a0 = apk[cp][wd0],   a1 = apk[cp][wd1];
      unsigned b0 = apk[cp+2][wd0], b1 = apk[cp+2][wd1];
      unsigned v0 = h ? a0 : b0;
      unsigned v1 = h ? a1 : b1;
      unsigned f0 = (unsigned)__shfl_xor((int)v0, 32);
      unsigned f1 = (unsigned)__shfl_xor((int)v1, 32);
      unsigned o0 = h ? b0 : a0;
      unsigned o1 = h ? b1 : a1;
      uint4 st;
      st.x = h ? f0 : o0;
      st.y = h ? f1 : o1;
      st.z = h ? o0 : f0;
      st.w = h ? o1 : f1;
      *(uint4*)&orow[cp*32 + jp*8] = st;
    }
  }
  if (lane < 32)
    ((float2*)ml)[(size_t)split*N + qrow] = make_float2(m_, l_);
}

// ---------------- merge partials + att_bias + residual + LayerNorm (exp2 domain)
template<int NS>
__global__ __launch_bounds__(256) void merge_ln(
    const unsigned short* __restrict__ opW, const float* __restrict__ ml,
    const float* __restrict__ x, const float* __restrict__ ab,
    const float* __restrict__ gam, const float* __restrict__ bet,
    float* __restrict__ out, int N){
  const int lane = threadIdx.x & 63;
  const long row = (long)blockIdx.x*4 + (threadIdx.x >> 6);
  float mm[NS], ll[NS];
  float M = -3.0e38f;
  #pragma unroll
  for (int i=0;i<NS;i++){
    float2 v = ((const float2*)ml)[(size_t)i*N + row];
    mm[i]=v.x; ll[i]=v.y;
    M = fmaxf(M, v.x);
  }
  float den = 0.f;
  float wgt[NS];
  #pragma unroll
  for (int i=0;i<NS;i++){ wgt[i] = exp2f(mm[i]-M)*ll[i]; den += wgt[i]; }
  float invd = 1.f/den;
  float o0 = 0.f, o1 = 0.f;
  #pragma unroll
  for (int i=0;i<NS;i++){
    unsigned u = *(const unsigned*)&opW[((size_t)i*N + row)*CC + lane*2];
    float c = wgt[i]*invd;
    o0 += c * bf2f((unsigned short)(u & 0xffffu));
    o1 += c * bf2f((unsigned short)(u >> 16));
  }
  float2 xb = ((const float2*)(x + row*CC))[lane];
  float2 bb = ((const float2*)ab)[lane];
  float a0 = o0 + bb.x + xb.x;
  float a1 = o1 + bb.y + xb.y;
  float s = a0 + a1, ss = a0*a0 + a1*a1;
  #pragma unroll
  for (int off=32; off; off>>=1){ s += __shfl_xor(s,off); ss += __shfl_xor(ss,off); }
  float mu  = s * (1.f/128.f);
  float var = ss * (1.f/128.f) - mu*mu;
  float rstd = rsqrtf(var + 1e-5f);
  float2 gg = ((const float2*)gam)[lane];
  float2 b2 = ((const float2*)bet)[lane];
  float2 r;
  r.x = (a0 - mu)*rstd*gg.x + b2.x;
  r.y = (a1 - mu)*rstd*gg.y + b2.y;
  ((float2*)(out + row*CC))[lane] = r;
}

extern "C" void kernel_launch(void* const* d_in, const int* in_sizes, int n_in,
                              void* d_out, int out_size, void* d_ws, size_t ws_size,
                              hipStream_t stream) {
  const float* x   = (const float*)d_in[0];
  const int*   ei  = (const int*)d_in[1];
  const float* W1  = (const float*)d_in[3];
  const float* a_s1= (const float*)d_in[4];
  const float* a_d1= (const float*)d_in[5];
  const float* b1  = (const float*)d_in[6];
  const float* W2  = (const float*)d_in[7];
  const float* a_s2= (const float*)d_in[8];
  const float* a_d2= (const float*)d_in[9];
  const float* b2  = (const float*)d_in[10];
  const float* Wa  = (const float*)d_in[11];
  const float* ab  = (const float*)d_in[12];
  const float* g   = (const float*)d_in[13];
  const float* be  = (const float*)d_in[14];
  float* out = (float*)d_out;

  const int N = in_sizes[0] / CC;
  const int E = in_sizes[1] / 2;
  const size_t MB = 1024*1024;
  const size_t KB = 1024;

  char* base = (char*)d_ws;
  // layout:
  //   [0,8M)   IMG (attn fragment image)
  //   [8,12M)  xwb bf16  (GAT phase; dead by attn)   -- overlaid by opW
  //   [12,16M) h bf16    (GAT + q-gen + pack; dead by attn)
  //   [16,18M) csrc | [18,18.7M) csr meta + as/ad | [19,19.1M) Wimg
  //   opW at [8, 8+4*ns M); ml after opW
  //   Qb bf16 lives in d_out (dead before merge_ln writes out)
  uint4* IMG  = (uint4*)(base);
  unsigned short* xwb = (unsigned short*)(base + 8*MB);
  unsigned short* hW  = (unsigned short*)(base + 12*MB);
  int* csrc   = (int*)(base + 16*MB);
  int* rowptr = (int*)(base + 18*MB);
  int* cursor = (int*)(base + 18*MB + 128*KB);
  int* deg    = (int*)(base + 18*MB + 256*KB);
  float* as_  = (float*)(base + 18*MB + 384*KB);
  float* ad_  = (float*)(base + 18*MB + 512*KB);
  unsigned short* Wimg = (unsigned short*)(base + 19*MB);
  unsigned short* opW  = (unsigned short*)(base + 8*MB);
  unsigned short* QbD  = (unsigned short*)d_out;

  const uint4* W1i = (const uint4*)(Wimg);
  const uint4* W2i = (const uint4*)(Wimg + 2048*8);
  const uint4* Wai = (const uint4*)(Wimg + 2*2048*8);

  const bool big = (ws_size >= 41*MB);   // ns=8 needs opW 32MB + ml
  const int ns = big ? 8 : 4;
  float* ml = (float*)(base + 8*MB + (size_t)ns*4*MB);

  dim3 B(256);

  // ---- weight fragment images + CSR build
  pack_w3<<<24, B, 0, stream>>>(W1, W2, Wa, Wimg);
  zero_int<<<(N+255)/256, B, 0, stream>>>(deg, N);
  csr_hist<<<(E+255)/256, B, 0, stream>>>(ei, deg, E);
  csr_scan<<<1, B, 0, stream>>>(deg, rowptr, cursor, N);
  csr_fill<<<(E+255)/256, B, 0, stream>>>(ei, cursor, csrc, E);

  // ---- GAT layer 1 (relu folded into gather epilogue)
  gemm_mfma<false,0><<<N/64, B, 0, stream>>>(x, W1i, xwb);
  rowdot2b<<<N/4, B, 0, stream>>>(xwb, a_s1, a_d1, as_, ad_);
  gat_gather<true><<<N/4, B, 0, stream>>>(rowptr, csrc, as_, ad_, xwb, b1, hW, N);

  // ---- GAT layer 2
  gemm_mfma<true,0><<<N/64, B, 0, stream>>>(hW, W2i, xwb);
  rowdot2b<<<N/4, B, 0, stream>>>(xwb, a_s2, a_d2, as_, ad_);
  gat_gather<false><<<N/4, B, 0, stream>>>(rowptr, csrc, as_, ad_, xwb, b2, hW, N);

  // ---- temporal attention (bf16 MFMA 32x32 flash)
  gemm_mfma<true,1><<<N/64, B, 0, stream>>>(hW, Wai, QbD);     // q bf16 (pre-scaled)
  if (big){
    convert_pack<1><<<(N*32)/256, B, 0, stream>>>(hW, IMG, N);
    attn_mfma<1><<<(N/128)*8, B, 0, stream>>>(QbD, IMG, opW, ml, N, 8);
    merge_ln<8><<<N/4, B, 0, stream>>>(opW, ml, x, ab, g, be, out, N);
  } else {
    convert_pack<2><<<(N*32)/256, B, 0, stream>>>(hW, IMG, N);
    attn_mfma<2><<<(N/128)*4, B, 0, stream>>>(QbD, IMG, opW, ml, N, 4);
    merge_ln<4><<<N/4, B, 0, stream>>>(opW, ml, x, ab, g, be, out, N);
  }
}

// Round 8
// 320.995 us; speedup vs baseline: 2.2001x; 1.0357x over previous
//
#include <hip/hip_runtime.h>

#define CC 128

typedef __attribute__((ext_vector_type(8))) short bf16x8;
typedef __attribute__((ext_vector_type(16))) float f32x16;

static __device__ __forceinline__ float lrelu(float v){ return v > 0.f ? v : 0.2f*v; }
static __device__ __forceinline__ unsigned short f2bf(float f){
  unsigned u = __float_as_uint(f);
  unsigned r = (u + 0x7fffu + ((u >> 16) & 1u)) >> 16;
  return (unsigned short)r;
}
static __device__ __forceinline__ float bf2f(unsigned short s){
  return __uint_as_float(((unsigned)s) << 16);
}
static __device__ __forceinline__ unsigned cvtpk(float lo, float hi){
  unsigned r;
  asm("v_cvt_pk_bf16_f32 %0, %1, %2" : "=v"(r) : "v"(lo), "v"(hi));
  return r;
}

#define QSCALE (0.08838834764831845f * 1.4426950408889634f)
#define L2E 1.4426950408889634f

#if defined(__has_builtin)
#if __has_builtin(__builtin_amdgcn_global_load_lds)
#define HAVE_GLL 1
#endif
#endif

#ifdef HAVE_GLL
static __device__ __forceinline__ void gload_lds16(const uint4* g, uint4* l){
  __builtin_amdgcn_global_load_lds(
      (const __attribute__((address_space(1))) unsigned int*)(const void*)g,
      (__attribute__((address_space(3))) unsigned int*)(void*)l, 16, 0, 0);
}
#endif

// ---------------- pack 3 weight matrices into MFMA B-fragment images
__global__ __launch_bounds__(256) void pack_w3(const float* __restrict__ W1,
                                               const float* __restrict__ W2,
                                               const float* __restrict__ Wa,
                                               unsigned short* __restrict__ img){
  int gid = blockIdx.x*256 + threadIdx.x;     // 0..6143
  int m = gid >> 11, u = gid & 2047;
  const float* W = (m==0) ? W1 : (m==1) ? W2 : Wa;
  int k = u >> 8, ct = (u >> 6) & 3, l = u & 63;
  int h = l >> 5, c = ct*32 + (l & 31);
  int k0 = k*16 + h*8;
  float f[8];
  #pragma unroll
  for (int j=0;j<8;j++) f[j] = W[(k0+j)*CC + c];
  uint4 o;
  o.x = cvtpk(f[0],f[1]); o.y = cvtpk(f[2],f[3]);
  o.z = cvtpk(f[4],f[5]); o.w = cvtpk(f[6],f[7]);
  *(uint4*)&img[((size_t)m*2048 + u)*8] = o;
}

// ---------------- MFMA GEMM: out_bf16[N,128] = A[N,128] @ W ; A f32 or bf16
// OMODE 0: plain bf16 out; 1: bf16 out scaled by QSCALE
template<bool ABF16, int OMODE>
__global__ __launch_bounds__(256) void gemm_mfma(const void* __restrict__ Av,
                                                 const uint4* __restrict__ Wimg,
                                                 unsigned short* __restrict__ out){
  __shared__ uint4 WS[2048];
  const int tid = threadIdx.x, lane = tid & 63, w = tid >> 6;
  const int h = lane >> 5, l31 = lane & 31;
  const long r0 = (long)blockIdx.x * 64;
#ifdef HAVE_GLL
  #pragma unroll
  for (int i=0;i<8;i++){ int u = i*256 + w*64; gload_lds16(Wimg + u + lane, &WS[u]); }
#else
  #pragma unroll
  for (int i=0;i<8;i++){ int u = i*256 + tid; WS[u] = Wimg[u]; }
#endif
  const int rt = w & 1, ct0 = (w >> 1) * 2;
  const long arow = (r0 + rt*32 + l31)*CC + h*8;
  f32x16 acc0 = {}, acc1 = {};
  __syncthreads();
  #pragma unroll
  for (int k=0;k<8;k++){
    bf16x8 afr;
    if (ABF16){
      afr = *(const bf16x8*)&((const unsigned short*)Av)[arow + k*16];
    } else {
      const float* ap = (const float*)Av + arow + k*16;
      float4 a0 = *(const float4*)ap;
      float4 a1 = *(const float4*)(ap+4);
      uint4 av;
      av.x = cvtpk(a0.x,a0.y); av.y = cvtpk(a0.z,a0.w);
      av.z = cvtpk(a1.x,a1.y); av.w = cvtpk(a1.z,a1.w);
      __builtin_memcpy(&afr, &av, 16);
    }
    bf16x8 b0 = *(const bf16x8*)&WS[(k*4+ct0  )*64 + lane];
    bf16x8 b1 = *(const bf16x8*)&WS[(k*4+ct0+1)*64 + lane];
    acc0 = __builtin_amdgcn_mfma_f32_32x32x16_bf16(afr, b0, acc0, 0,0,0);
    acc1 = __builtin_amdgcn_mfma_f32_32x32x16_bf16(afr, b1, acc1, 0,0,0);
  }
  #pragma unroll
  for (int r=0;r<16;r++){
    long row = r0 + rt*32 + (r&3) + 8*(r>>2) + 4*h;
    float s0 = (OMODE==1) ? acc0[r]*QSCALE : acc0[r];
    float s1 = (OMODE==1) ? acc1[r]*QSCALE : acc1[r];
    out[row*CC + ct0*32 + l31]     = f2bf(s0);
    out[row*CC + (ct0+1)*32 + l31] = f2bf(s1);
  }
}

// ---------------- per-row dot with two vectors (bf16 rows)
__global__ __launch_bounds__(256) void rowdot2b(const unsigned short* __restrict__ X,
                                                const float* __restrict__ a1,
                                                const float* __restrict__ a2,
                                                float* __restrict__ as_, float* __restrict__ ad_){
  const int lane = threadIdx.x & 63;
  const long row = (long)blockIdx.x*4 + (threadIdx.x >> 6);
  unsigned u = *(const unsigned*)&X[row*CC + lane*2];
  float v0 = bf2f((unsigned short)(u & 0xffffu));
  float v1 = bf2f((unsigned short)(u >> 16));
  float2 w1 = ((const float2*)a1)[lane];
  float2 w2 = ((const float2*)a2)[lane];
  float s1 = v0*w1.x + v1*w1.y;
  float s2 = v0*w2.x + v1*w2.y;
  #pragma unroll
  for (int off=32; off; off>>=1){
    s1 += __shfl_xor(s1, off);
    s2 += __shfl_xor(s2, off);
  }
  if (lane==0){ as_[row]=s1; ad_[row]=s2; }
}

// ---------------- CSR build (edge_index identical for both layers)
__global__ void zero_int(int* __restrict__ p, int n){
  int i = blockIdx.x*256 + threadIdx.x;
  if (i < n) p[i] = 0;
}
__global__ void csr_hist(const int* __restrict__ ei, int* __restrict__ deg, int E){
  int e = blockIdx.x*256 + threadIdx.x;
  if (e < E) atomicAdd(&deg[ei[E + e]], 1);
}
__global__ __launch_bounds__(256) void csr_scan(const int* __restrict__ deg,
                                                int* __restrict__ rowptr,
                                                int* __restrict__ cursor, int N){
  __shared__ int part[257];
  const int t = threadIdx.x;
  const int per = N / 256;
  const int base = t*per;
  int s = 0;
  for (int j=0;j<per;j++) s += deg[base+j];
  part[t+1] = s;
  if (t==0) part[0] = 0;
  __syncthreads();
  if (t==0){
    for (int i=1;i<=256;i++) part[i] += part[i-1];
  }
  __syncthreads();
  int run = part[t];
  for (int j=0;j<per;j++){
    rowptr[base+j] = run;
    cursor[base+j] = run;
    run += deg[base+j];
  }
  if (t==255) rowptr[N] = run;
}
__global__ void csr_fill(const int* __restrict__ ei, int* __restrict__ cursor,
                         int* __restrict__ csrc, int E){
  int e = blockIdx.x*256 + threadIdx.x;
  if (e < E){
    int d = ei[E + e];
    int slot = atomicAdd(&cursor[d], 1);
    csrc[slot] = ei[e];
  }
}

// ---------------- fused GAT: lane-parallel segment softmax + weighted gather (bf16)
template<bool RELUOUT>
__global__ __launch_bounds__(256) void gat_gather(
    const int* __restrict__ rowptr, const int* __restrict__ csrc,
    const float* __restrict__ as_, const float* __restrict__ ad_,
    const unsigned short* __restrict__ X, const float* __restrict__ b,
    unsigned short* __restrict__ O, int N){
  const int lane = threadIdx.x & 63;
  const int half = lane >> 5, l32 = lane & 31;
  const int dst = blockIdx.x*4 + (threadIdx.x >> 6);
  const float adv = ad_[dst];
  float m = lrelu(as_[dst] + adv);       // self-loop
  float l = 1.f;
  float acc0=0.f, acc1=0.f, acc2=0.f, acc3=0.f;
  if (half == 0){
    ushort4 v = *(const ushort4*)&X[(size_t)dst*CC + l32*4];
    acc0 = bf2f(v.x); acc1 = bf2f(v.y); acc2 = bf2f(v.z); acc3 = bf2f(v.w);
  }
  const int kb = rowptr[dst];
  const int deg = rowptr[dst+1] - kb;
  for (int c0 = 0; c0 < deg; c0 += 64){
    const int nv = min(64, deg - c0);
    int src = dst; float e = -3.0e38f;
    if (lane < nv){
      src = csrc[kb + c0 + lane];
      e = lrelu(as_[src] + adv);
    }
    float cm = e;
    #pragma unroll
    for (int off=32; off; off>>=1) cm = fmaxf(cm, __shfl_xor(cm, off));
    if (cm > m){
      float fr = __builtin_amdgcn_exp2f((m - cm)*L2E);
      l *= fr; acc0 *= fr; acc1 *= fr; acc2 *= fr; acc3 *= fr;
      m = cm;
    }
    float p = __builtin_amdgcn_exp2f((e - m)*L2E);   // 0 for invalid lanes
    float cs = p;
    #pragma unroll
    for (int off=32; off; off>>=1) cs += __shfl_xor(cs, off);
    l += cs;
    for (int j = 0; j < nv; j += 2){
      float w0 = __shfl(p, j);
      float w1 = __shfl(p, (j+1)&63);
      w1 = (j+1 < nv) ? w1 : 0.f;
      int s0 = __shfl(src, j);
      int s1 = __shfl(src, (j+1)&63);
      float wgt = half ? w1 : w0;
      int s = half ? s1 : s0;
      ushort4 v = *(const ushort4*)&X[(size_t)s*CC + l32*4];
      acc0 += wgt*bf2f(v.x); acc1 += wgt*bf2f(v.y);
      acc2 += wgt*bf2f(v.z); acc3 += wgt*bf2f(v.w);
    }
  }
  acc0 += __shfl_xor(acc0, 32);
  acc1 += __shfl_xor(acc1, 32);
  acc2 += __shfl_xor(acc2, 32);
  acc3 += __shfl_xor(acc3, 32);
  if (half == 0){
    float inv = 1.f / l;
    float4 bb = *(const float4*)&b[l32*4];
    float r0 = acc0*inv + bb.x, r1 = acc1*inv + bb.y;
    float r2 = acc2*inv + bb.z, r3 = acc3*inv + bb.w;
    if (RELUOUT){
      r0=fmaxf(r0,0.f); r1=fmaxf(r1,0.f); r2=fmaxf(r2,0.f); r3=fmaxf(r3,0.f);
    }
    uint2 o; o.x = cvtpk(r0,r1); o.y = cvtpk(r2,r3);
    *(uint2*)&O[(size_t)dst*CC + l32*4] = o;
  }
}

// ---------------- h (bf16) -> IMG fragment image; per KVB-key tile: NKT*1024 uint4
template<int NKT>
__global__ __launch_bounds__(256) void convert_pack(const unsigned short* __restrict__ h,
                                                    uint4* __restrict__ IMG, int N){
  const int KVB = NKT*32;
  int idx = blockIdx.x*256 + threadIdx.x;
  int tile = idx / (NKT*1024);
  int u = idx - tile*(NKT*1024);
  int l = u & 63, hh = l >> 5, l31 = l & 31;
  if (u < NKT*512){
    int kt = u >> 9, ks = (u >> 6) & 7;
    int key = tile*KVB + kt*32 + l31;
    IMG[idx] = *(const uint4*)&h[(size_t)key*CC + ks*16 + hh*8];
  } else {
    int v = u - NKT*512;
    int ks = (v >> 6) & (2*NKT - 1);
    int ct = v >> (NKT==1 ? 7 : 8);
    int c = ct*32 + l31;
    int key0 = tile*KVB + ks*16 + hh*8;
    unsigned short o[8];
    #pragma unroll
    for (int j=0;j<8;j++) o[j] = h[(size_t)(key0+j)*CC + c];
    IMG[idx] = *(uint4*)o;
  }
}

// ---------------- MFMA flash attention (bf16, 32x32x16)
// NKT: KV tile = NKT*32 keys; NQT: q sub-tiles per wave (32 q each).
// Each LDS H-fragment read feeds NQT MFMAs (register reuse on Q).
template<int NKT, int NQT>
__global__ __launch_bounds__(256,2) void attn_mfma(
    const unsigned short* __restrict__ Qb, const uint4* __restrict__ IMG,
    unsigned short* __restrict__ opW, float* __restrict__ ml, int N, int nsplit){
  const int TILE4 = NKT*1024;
  __shared__ uint4 SH[2*NKT*1024];

  const int tid = threadIdx.x;
  const int lane = tid & 63, w = tid >> 6;
  const int h = lane >> 5, q31 = lane & 31;
  // XCD-pinning swizzle: split = flat % nsplit (matches round-robin XCD assignment)
  const int flat = blockIdx.x;
  const int split = flat % nsplit;
  const int qb0 = (flat / nsplit) * (128*NQT);
  const int KVB = NKT*32;
  const int ntt = N / KVB;
  const int tb = (ntt*split)/nsplit, te = (ntt*(split+1))/nsplit;

  int qrow[NQT];
  bf16x8 qf[NQT][8];
  #pragma unroll
  for (int qt=0; qt<NQT; qt++){
    qrow[qt] = qb0 + w*(32*NQT) + qt*32 + q31;
    #pragma unroll
    for (int ks=0; ks<8; ks++)
      qf[qt][ks] = *(const bf16x8*)&Qb[(size_t)qrow[qt]*CC + ks*16 + h*8];
  }

  f32x16 zero16 = {};
  f32x16 acc_o[4][NQT];
  #pragma unroll
  for (int ct=0; ct<4; ct++)
    #pragma unroll
    for (int qt=0; qt<NQT; qt++) acc_o[ct][qt] = zero16;
  float m_[NQT], l_[NQT];
  #pragma unroll
  for (int qt=0; qt<NQT; qt++){ m_[qt] = -3.0e38f; l_[qt] = 0.f; }

  int cur = 0;
  {
    const uint4* src = IMG + (size_t)tb*TILE4;
#ifdef HAVE_GLL
    #pragma unroll
    for (int i=0;i<NKT*4;i++){ int u = i*256 + w*64; gload_lds16(src + u + lane, &SH[u]); }
#else
    #pragma unroll
    for (int i=0;i<NKT*4;i++){ int u = i*256 + tid; SH[u] = src[u]; }
#endif
  }

  for (int t=tb; t<te; t++){
    __syncthreads();
    if (t+1 < te){
      const uint4* src = IMG + (size_t)(t+1)*TILE4;
      uint4* dst = &SH[(cur^1)*TILE4];
#ifdef HAVE_GLL
      #pragma unroll
      for (int i=0;i<NKT*4;i++){ int u = i*256 + w*64; gload_lds16(src + u + lane, dst + u); }
#else
      #pragma unroll
      for (int i=0;i<NKT*4;i++){ int u = i*256 + tid; dst[u] = src[u]; }
#endif
    }
    const uint4* B = &SH[cur*TILE4];

    // ---- S phase: each hf read feeds NQT MFMAs
    f32x16 accs[NKT][NQT];
    #pragma unroll
    for (int kt=0; kt<NKT; kt++){
      #pragma unroll
      for (int qt=0; qt<NQT; qt++) accs[kt][qt] = zero16;
      __builtin_amdgcn_s_setprio(1);
      #pragma unroll
      for (int ks=0; ks<8; ks++){
        bf16x8 hf = *(const bf16x8*)&B[(kt*8+ks)*64 + lane];
        #pragma unroll
        for (int qt=0; qt<NQT; qt++)
          accs[kt][qt] = __builtin_amdgcn_mfma_f32_32x32x16_bf16(hf, qf[qt][ks], accs[kt][qt], 0,0,0);
      }
      __builtin_amdgcn_s_setprio(0);
    }

    // ---- online softmax (exp2 domain), defer-max; tree reductions
    float tm[NQT];
    #pragma unroll
    for (int qt=0; qt<NQT; qt++){
      float tmax[16];
      #pragma unroll
      for (int r=0;r<16;r++){
        float v = accs[0][qt][r];
        if (NKT == 2) v = fmaxf(v, accs[1][qt][r]);
        tmax[r] = v;
      }
      #pragma unroll
      for (int s=8; s; s>>=1)
        #pragma unroll
        for (int r=0;r<s;r++) tmax[r] = fmaxf(tmax[r], tmax[r+s]);
      tm[qt] = fmaxf(tmax[0], __shfl_xor(tmax[0], 32));
    }
    bool ok = true;
    #pragma unroll
    for (int qt=0; qt<NQT; qt++) ok &= (tm[qt] <= m_[qt] + 11.0f);
    if (!__all(ok)){
      #pragma unroll
      for (int qt=0; qt<NQT; qt++){
        float mn = fmaxf(m_[qt], tm[qt]);
        float fr = __builtin_amdgcn_exp2f(m_[qt] - mn);
        m_[qt] = mn; l_[qt] *= fr;
        #pragma unroll
        for (int ct=0; ct<4; ct++)
          #pragma unroll
          for (int r=0;r<16;r++) acc_o[ct][qt][r] *= fr;
      }
    }
    unsigned pk[NQT][NKT][8];
    #pragma unroll
    for (int qt=0; qt<NQT; qt++){
      float psum[16];
      #pragma unroll
      for (int kt=0; kt<NKT; kt++)
        #pragma unroll
        for (int r=0;r<16;r++)
          accs[kt][qt][r] = __builtin_amdgcn_exp2f(accs[kt][qt][r] - m_[qt]);
      #pragma unroll
      for (int r=0;r<16;r++){
        float v = accs[0][qt][r];
        if (NKT == 2) v += accs[1][qt][r];
        psum[r] = v;
      }
      #pragma unroll
      for (int s=8; s; s>>=1)
        #pragma unroll
        for (int r=0;r<s;r++) psum[r] += psum[r+s];
      l_[qt] += psum[0] + __shfl_xor(psum[0], 32);
      #pragma unroll
      for (int kt=0; kt<NKT; kt++)
        #pragma unroll
        for (int wd=0; wd<8; wd++)
          pk[qt][kt][wd] = cvtpk(accs[kt][qt][2*wd], accs[kt][qt][2*wd+1]);
    }

    // ---- PV: in-register P^T frag assembly; each hf read feeds NQT MFMAs
    #pragma unroll
    for (int ks=0; ks<2*NKT; ks++){
      const int kt = ks >> 1, W = (ks & 1)*4;
      bf16x8 pfrag[NQT];
      #pragma unroll
      for (int qt=0; qt<NQT; qt++){
        unsigned w0o = pk[qt][kt][W+0], w1o = pk[qt][kt][W+1];
        unsigned w2o = pk[qt][kt][W+2], w3o = pk[qt][kt][W+3];
        unsigned va = h ? w0o : w2o;
        unsigned vb = h ? w1o : w3o;
        unsigned fa = (unsigned)__shfl_xor((int)va, 32);
        unsigned fb = (unsigned)__shfl_xor((int)vb, 32);
        uint4 fw;
        fw.x = h ? fa : w0o;
        fw.y = h ? fb : w1o;
        fw.z = h ? w2o : fa;
        fw.w = h ? w3o : fb;
        __builtin_memcpy(&pfrag[qt], &fw, 16);
      }
      __builtin_amdgcn_s_setprio(1);
      #pragma unroll
      for (int ct=0; ct<4; ct++){
        bf16x8 hf = *(const bf16x8*)&B[NKT*512 + (ct*2*NKT+ks)*64 + lane];
        #pragma unroll
        for (int qt=0; qt<NQT; qt++)
          acc_o[ct][qt] = __builtin_amdgcn_mfma_f32_32x32x16_bf16(hf, pfrag[qt], acc_o[ct][qt], 0,0,0);
      }
      __builtin_amdgcn_s_setprio(0);
    }
    cur ^= 1;
  }

  // ---- epilogue: per qt: normalize, shfl-transpose halves, contiguous stores
  #pragma unroll
  for (int qt=0; qt<NQT; qt++){
    float inv = 1.f / l_[qt];
    unsigned apk[4][8];
    #pragma unroll
    for (int ct=0; ct<4; ct++)
      #pragma unroll
      for (int wd=0; wd<8; wd++)
        apk[ct][wd] = cvtpk(acc_o[ct][qt][2*wd]*inv, acc_o[ct][qt][2*wd+1]*inv);

    unsigned short* orow = opW + (size_t)split*N*CC + (size_t)qrow[qt]*CC + h*64;
    #pragma unroll
    for (int cp=0; cp<2; cp++){
      #pragma unroll
      for (int jp=0; jp<4; jp++){
        int wd0 = 2*jp, wd1 = 2*jp+1;
        unsigned a0 = apk[cp][wd0],   a1 = apk[cp][wd1];
        unsigned b0 = apk[cp+2][wd0], b1 = apk[cp+2][wd1];
        unsigned v0 = h ? a0 : b0;
        unsigned v1 = h ? a1 : b1;
        unsigned f0 = (unsigned)__shfl_xor((int)v0, 32);
        unsigned f1 = (unsigned)__shfl_xor((int)v1, 32);
        unsigned o0 = h ? b0 : a0;
        unsigned o1 = h ? b1 : a1;
        uint4 st;
        st.x = h ? f0 : o0;
        st.y = h ? f1 : o1;
        st.z = h ? o0 : f0;
        st.w = h ? o1 : f1;
        *(uint4*)&orow[cp*32 + jp*8] = st;
      }
    }
    if (lane < 32)
      ((float2*)ml)[(size_t)split*N + qrow[qt]] = make_float2(m_[qt], l_[qt]);
  }
}

// ---------------- merge partials + att_bias + residual + LayerNorm (exp2 domain)
template<int NS>
__global__ __launch_bounds__(256) void merge_ln(
    const unsigned short* __restrict__ opW, const float* __restrict__ ml,
    const float* __restrict__ x, const float* __restrict__ ab,
    const float* __restrict__ gam, const float* __restrict__ bet,
    float* __restrict__ out, int N){
  const int lane = threadIdx.x & 63;
  const long row = (long)blockIdx.x*4 + (threadIdx.x >> 6);
  float mm[NS], ll[NS];
  float M = -3.0e38f;
  #pragma unroll
  for (int i=0;i<NS;i++){
    float2 v = ((const float2*)ml)[(size_t)i*N + row];
    mm[i]=v.x; ll[i]=v.y;
    M = fmaxf(M, v.x);
  }
  float den = 0.f;
  float wgt[NS];
  #pragma unroll
  for (int i=0;i<NS;i++){ wgt[i] = exp2f(mm[i]-M)*ll[i]; den += wgt[i]; }
  float invd = 1.f/den;
  float o0 = 0.f, o1 = 0.f;
  #pragma unroll
  for (int i=0;i<NS;i++){
    unsigned u = *(const unsigned*)&opW[((size_t)i*N + row)*CC + lane*2];
    float c = wgt[i]*invd;
    o0 += c * bf2f((unsigned short)(u & 0xffffu));
    o1 += c * bf2f((unsigned short)(u >> 16));
  }
  float2 xb = ((const float2*)(x + row*CC))[lane];
  float2 bb = ((const float2*)ab)[lane];
  float a0 = o0 + bb.x + xb.x;
  float a1 = o1 + bb.y + xb.y;
  float s = a0 + a1, ss = a0*a0 + a1*a1;
  #pragma unroll
  for (int off=32; off; off>>=1){ s += __shfl_xor(s,off); ss += __shfl_xor(ss,off); }
  float mu  = s * (1.f/128.f);
  float var = ss * (1.f/128.f) - mu*mu;
  float rstd = rsqrtf(var + 1e-5f);
  float2 gg = ((const float2*)gam)[lane];
  float2 b2 = ((const float2*)bet)[lane];
  float2 r;
  r.x = (a0 - mu)*rstd*gg.x + b2.x;
  r.y = (a1 - mu)*rstd*gg.y + b2.y;
  ((float2*)(out + row*CC))[lane] = r;
}

extern "C" void kernel_launch(void* const* d_in, const int* in_sizes, int n_in,
                              void* d_out, int out_size, void* d_ws, size_t ws_size,
                              hipStream_t stream) {
  const float* x   = (const float*)d_in[0];
  const int*   ei  = (const int*)d_in[1];
  const float* W1  = (const float*)d_in[3];
  const float* a_s1= (const float*)d_in[4];
  const float* a_d1= (const float*)d_in[5];
  const float* b1  = (const float*)d_in[6];
  const float* W2  = (const float*)d_in[7];
  const float* a_s2= (const float*)d_in[8];
  const float* a_d2= (const float*)d_in[9];
  const float* b2  = (const float*)d_in[10];
  const float* Wa  = (const float*)d_in[11];
  const float* ab  = (const float*)d_in[12];
  const float* g   = (const float*)d_in[13];
  const float* be  = (const float*)d_in[14];
  float* out = (float*)d_out;

  const int N = in_sizes[0] / CC;
  const int E = in_sizes[1] / 2;
  const size_t MB = 1024*1024;
  const size_t KB = 1024;

  char* base = (char*)d_ws;
  uint4* IMG  = (uint4*)(base);
  unsigned short* xwb = (unsigned short*)(base + 8*MB);
  unsigned short* hW  = (unsigned short*)(base + 12*MB);
  int* csrc   = (int*)(base + 16*MB);
  int* rowptr = (int*)(base + 18*MB);
  int* cursor = (int*)(base + 18*MB + 128*KB);
  int* deg    = (int*)(base + 18*MB + 256*KB);
  float* as_  = (float*)(base + 18*MB + 384*KB);
  float* ad_  = (float*)(base + 18*MB + 512*KB);
  unsigned short* Wimg = (unsigned short*)(base + 19*MB);
  unsigned short* opW  = (unsigned short*)(base + 8*MB);
  unsigned short* QbD  = (unsigned short*)d_out;

  const uint4* W1i = (const uint4*)(Wimg);
  const uint4* W2i = (const uint4*)(Wimg + 2048*8);
  const uint4* Wai = (const uint4*)(Wimg + 2*2048*8);

  const bool big = (ws_size >= 41*MB);   // ns=8 needs opW 32MB + ml
  const int ns = big ? 8 : 4;
  float* ml = (float*)(base + 8*MB + (size_t)ns*4*MB);

  dim3 B(256);

  // ---- weight fragment images + CSR build
  pack_w3<<<24, B, 0, stream>>>(W1, W2, Wa, Wimg);
  zero_int<<<(N+255)/256, B, 0, stream>>>(deg, N);
  csr_hist<<<(E+255)/256, B, 0, stream>>>(ei, deg, E);
  csr_scan<<<1, B, 0, stream>>>(deg, rowptr, cursor, N);
  csr_fill<<<(E+255)/256, B, 0, stream>>>(ei, cursor, csrc, E);

  // ---- GAT layer 1 (relu folded into gather epilogue)
  gemm_mfma<false,0><<<N/64, B, 0, stream>>>(x, W1i, xwb);
  rowdot2b<<<N/4, B, 0, stream>>>(xwb, a_s1, a_d1, as_, ad_);
  gat_gather<true><<<N/4, B, 0, stream>>>(rowptr, csrc, as_, ad_, xwb, b1, hW, N);

  // ---- GAT layer 2
  gemm_mfma<true,0><<<N/64, B, 0, stream>>>(hW, W2i, xwb);
  rowdot2b<<<N/4, B, 0, stream>>>(xwb, a_s2, a_d2, as_, ad_);
  gat_gather<false><<<N/4, B, 0, stream>>>(rowptr, csrc, as_, ad_, xwb, b2, hW, N);

  // ---- temporal attention (bf16 MFMA 32x32 flash)
  gemm_mfma<true,1><<<N/64, B, 0, stream>>>(hW, Wai, QbD);     // q bf16 (pre-scaled)
  if (big){
    convert_pack<1><<<(N*32)/256, B, 0, stream>>>(hW, IMG, N);
    attn_mfma<1,2><<<(N/256)*8, B, 0, stream>>>(QbD, IMG, opW, ml, N, 8);
    merge_ln<8><<<N/4, B, 0, stream>>>(opW, ml, x, ab, g, be, out, N);
  } else {
    convert_pack<2><<<(N*32)/256, B, 0, stream>>>(hW, IMG, N);
    attn_mfma<2,1><<<(N/128)*4, B, 0, stream>>>(QbD, IMG, opW, ml, N, 4);
    merge_ln<4><<<N/4, B, 0, stream>>>(opW, ml, x, ab, g, be, out, N);
  }
}